// Round 1
// baseline (2193.985 us; speedup 1.0000x reference)
//
#include <hip/hip_runtime.h>
#include <cmath>

// ---------------------------------------------------------------------------
// Poincare transformer layer, fp32 correctness-first implementation.
// B=4, S=1024, D=1024, H=16, HD=64, FF=4096.  N = B*S = 4096 tokens.
// Workspace requirement: (24576 + 4*4194304 + 16777216) * 4 B  ~= 134 MB.
// ---------------------------------------------------------------------------

constexpr int kD  = 1024;
constexpr int kH  = 16;
constexpr int kHD = 64;
constexpr int kFF = 4096;
constexpr int kB  = 4;
constexpr int kS  = 1024;
constexpr int kN  = kB * kS;   // 4096 tokens

#define EPSF 1e-7f
#define MTAF (1.0f - 1e-5f)

// ---------------- math helpers ----------------
__device__ __forceinline__ float atanh_clipped(float n) {
  // arctanh(min(n, 1-1e-5)), n assumed >= 0
  float c = fminf(n, MTAF);
  return 0.5f * logf((1.0f + c) / (1.0f - c));
}
__device__ __forceinline__ float logmap0_scale(float nraw) {
  float n = fmaxf(nraw, EPSF);
  return atanh_clipped(n) / n;
}
__device__ __forceinline__ float expmap0_scale(float nraw) {
  float n = fmaxf(nraw, EPSF);
  return tanhf(n) / n;
}
// scale s such that logmap0(expmap0(v)) = s*v, per reference clip semantics
__device__ __forceinline__ float roundtrip_scale(float nraw) {
  float nu = fmaxf(nraw, EPSF);
  float se = tanhf(nu) / nu;
  float nb = fmaxf(se * nraw, EPSF);
  float sl = atanh_clipped(nb) / nb;
  return sl * se;
}

// ---------------- reductions ----------------
__device__ __forceinline__ float blockReduceSum256(float v, float* s4) {
#pragma unroll
  for (int o = 32; o > 0; o >>= 1) v += __shfl_xor(v, o);
  int wave = threadIdx.x >> 6;
  if ((threadIdx.x & 63) == 0) s4[wave] = v;
  __syncthreads();
  float r = s4[0] + s4[1] + s4[2] + s4[3];
  __syncthreads();
  return r;
}
__device__ __forceinline__ float waveReduceSum64(float v) {
#pragma unroll
  for (int o = 32; o > 0; o >>= 1) v += __shfl_xor(v, o);
  return v;
}
__device__ __forceinline__ float redSum16(float v) {
#pragma unroll
  for (int o = 8; o > 0; o >>= 1) v += __shfl_xor(v, o);
  return v;
}
__device__ __forceinline__ float redMax16(float v) {
#pragma unroll
  for (int o = 8; o > 0; o >>= 1) v = fmaxf(v, __shfl_xor(v, o));
  return v;
}

// ---------------- ada = t_emb @ w_ada + b_ada ----------------
// grid: (6D/256, B), block 256
__global__ __launch_bounds__(256) void k_ada(const float* __restrict__ t_emb,
                                             const float* __restrict__ w_ada,
                                             const float* __restrict__ b_ada,
                                             float* __restrict__ ada) {
  __shared__ float te[kD];
  int b = blockIdx.y;
  for (int i = threadIdx.x; i < kD; i += 256) te[i] = t_emb[b * kD + i];
  __syncthreads();
  int col = blockIdx.x * 256 + threadIdx.x;  // 0..6143
  float acc = b_ada[col];
  for (int k = 0; k < kD; ++k) acc += te[k] * w_ada[(size_t)k * (6 * kD) + col];
  ada[b * 6 * kD + col] = acc;
}

// ---------------- prenorm: lx = rt( layernorm(logmap0(x))*(1+sc)+sh ) ----------------
// grid: N blocks, 256 threads
__global__ __launch_bounds__(256) void k_prenorm(const float* __restrict__ x,
                                                 const float* __restrict__ ada,
                                                 int sh_off, int sc_off,
                                                 float* __restrict__ out) {
  __shared__ float sred[4];
  int tok = blockIdx.x;
  int b = tok >> 10;  // S = 1024
  const float* xp = x + (size_t)tok * kD;
  float xv[4];
  float ss = 0.f;
#pragma unroll
  for (int i = 0; i < 4; ++i) {
    xv[i] = xp[i * 256 + threadIdx.x];
    ss += xv[i] * xv[i];
  }
  ss = blockReduceSum256(ss, sred);
  float sl = logmap0_scale(sqrtf(ss));
  float sum = 0.f;
#pragma unroll
  for (int i = 0; i < 4; ++i) { xv[i] *= sl; sum += xv[i]; }
  sum = blockReduceSum256(sum, sred);
  float mean = sum * (1.0f / kD);
  float vs = 0.f;
#pragma unroll
  for (int i = 0; i < 4; ++i) { xv[i] -= mean; vs += xv[i] * xv[i]; }
  vs = blockReduceSum256(vs, sred);
  float inv = rsqrtf(vs * (1.0f / kD) + 1e-6f);
  const float* shp = ada + b * 6 * kD + sh_off;
  const float* scp = ada + b * 6 * kD + sc_off;
  float uu = 0.f;
#pragma unroll
  for (int i = 0; i < 4; ++i) {
    int d = i * 256 + threadIdx.x;
    float u = xv[i] * inv * (1.0f + scp[d]) + shp[d];
    xv[i] = u;
    uu += u * u;
  }
  uu = blockReduceSum256(uu, sred);
  float s = roundtrip_scale(sqrtf(uu));
  float* op = out + (size_t)tok * kD;
#pragma unroll
  for (int i = 0; i < 4; ++i) op[i * 256 + threadIdx.x] = s * xv[i];
}

// ---------------- generic fp32 GEMM: C = A @ W + bias ----------------
// 128x128 tile, BK=16, 256 threads, 8x8 per thread. blockIdx.z selects W/bias/C.
__global__ __launch_bounds__(256) void k_gemm(const float* __restrict__ A,
                                              const float* __restrict__ W0,
                                              const float* __restrict__ W1,
                                              const float* __restrict__ W2,
                                              const float* __restrict__ bias0,
                                              const float* __restrict__ bias1,
                                              const float* __restrict__ bias2,
                                              float* __restrict__ C0,
                                              float* __restrict__ C1,
                                              float* __restrict__ C2,
                                              int M, int N, int K) {
  const float* W = (blockIdx.z == 0) ? W0 : ((blockIdx.z == 1) ? W1 : W2);
  const float* bias = (blockIdx.z == 0) ? bias0 : ((blockIdx.z == 1) ? bias1 : bias2);
  float* C = (blockIdx.z == 0) ? C0 : ((blockIdx.z == 1) ? C1 : C2);

  __shared__ __align__(16) float As[16][128];  // [k][m]
  __shared__ __align__(16) float Bs[16][128];  // [k][n]
  int tid = threadIdx.x;
  int tn = tid & 15, tm = tid >> 4;
  int row0 = blockIdx.y * 128, col0 = blockIdx.x * 128;

  float acc[8][8];
#pragma unroll
  for (int i = 0; i < 8; ++i)
#pragma unroll
    for (int j = 0; j < 8; ++j) acc[i][j] = 0.f;

  for (int k0 = 0; k0 < K; k0 += 16) {
    __syncthreads();
#pragma unroll
    for (int p = 0; p < 8; ++p) {
      int idx = p * 256 + tid;
      int r = idx >> 4, kk = idx & 15;          // A tile: 128 rows x 16 k
      As[kk][r] = A[(size_t)(row0 + r) * K + k0 + kk];
      int r2 = idx >> 7, c2 = idx & 127;        // B tile: 16 k x 128 cols
      Bs[r2][c2] = W[(size_t)(k0 + r2) * N + col0 + c2];
    }
    __syncthreads();
#pragma unroll
    for (int kk = 0; kk < 16; ++kk) {
      float a8[8], b8[8];
      *(float4*)&a8[0] = *(const float4*)&As[kk][tm * 8];
      *(float4*)&a8[4] = *(const float4*)&As[kk][tm * 8 + 4];
      *(float4*)&b8[0] = *(const float4*)&Bs[kk][tn * 8];
      *(float4*)&b8[4] = *(const float4*)&Bs[kk][tn * 8 + 4];
#pragma unroll
      for (int i = 0; i < 8; ++i)
#pragma unroll
        for (int j = 0; j < 8; ++j) acc[i][j] += a8[i] * b8[j];
    }
  }
  float bv[8];
#pragma unroll
  for (int j = 0; j < 8; ++j) bv[j] = bias[col0 + tn * 8 + j];
#pragma unroll
  for (int i = 0; i < 8; ++i) {
    size_t off = (size_t)(row0 + tm * 8 + i) * N + col0 + tn * 8;
    float4 r0, r1;
    r0.x = acc[i][0] + bv[0]; r0.y = acc[i][1] + bv[1];
    r0.z = acc[i][2] + bv[2]; r0.w = acc[i][3] + bv[3];
    r1.x = acc[i][4] + bv[4]; r1.y = acc[i][5] + bv[5];
    r1.z = acc[i][6] + bv[6]; r1.w = acc[i][7] + bv[7];
    *(float4*)&C[off] = r0;
    *(float4*)&C[off + 4] = r1;
  }
}

// ---------------- head split: q_t -> qt (in place), for q,k,v ----------------
// per token block; folds _to_heads + logmap0 into per-head scalar scales.
__global__ __launch_bounds__(256) void k_headsplit(float* __restrict__ q,
                                                   float* __restrict__ k,
                                                   float* __restrict__ v,
                                                   float ratio /* BETA_H/BETA_N */) {
  __shared__ float sh[16];
  int tok = blockIdx.x;
  int tid = threadIdx.x, wave = tid >> 6;
  float* ptrs[3] = {q, k, v};
#pragma unroll
  for (int t = 0; t < 3; ++t) {
    float* p = ptrs[t] + (size_t)tok * kD;
    float val[4], hs[4];
#pragma unroll
    for (int i = 0; i < 4; ++i) {
      val[i] = p[i * 256 + tid];
      hs[i] = waveReduceSum64(val[i] * val[i]);  // head (i*4 + wave) sumsq
    }
    if ((tid & 63) == 0) {
#pragma unroll
      for (int i = 0; i < 4; ++i) sh[i * 4 + wave] = hs[i];
    }
    __syncthreads();
    float tot = 0.f;
#pragma unroll
    for (int j = 0; j < 16; ++j) tot += sh[j];
    float s1 = roundtrip_scale(sqrtf(tot));  // full-dim logmap0(expmap0(q_t))
    float c = s1 * ratio;
#pragma unroll
    for (int i = 0; i < 4; ++i) {
      float m = c * sqrtf(hs[i]);            // |z_h|
      float s2 = roundtrip_scale(m);         // per-head expmap0 then logmap0
      p[i * 256 + tid] = c * s2 * val[i];
    }
    __syncthreads();  // before next tensor reuses sh
  }
}

// ---------------- flash attention + out-head scaling ----------------
// grid: (S/64, B*H), block 256. qt/kt/vt layout [N, D] with head chunk h*64.
// Writes ao[token, h*64+d] = rt(|w|) * (BETA_N/BETA_H) * w  (w = attn @ vt row)
__global__ __launch_bounds__(256) void k_attn(const float* __restrict__ qt,
                                              const float* __restrict__ kt,
                                              const float* __restrict__ vt,
                                              float* __restrict__ ao,
                                              float ratio2 /* BETA_N/BETA_H */) {
  __shared__ __align__(16) float Qs[64][68];
  __shared__ __align__(16) float KPs[64][68];  // K tile, reused as P tile
  __shared__ __align__(16) float Vs[64][68];
  int bh = blockIdx.y;
  int b = bh >> 4, h = bh & 15;
  int q0 = blockIdx.x * 64;
  int tid = threadIdx.x;
  int tq = tid >> 4, tn = tid & 15;

  for (int i = tid; i < 64 * 64; i += 256) {
    int r = i >> 6, d = i & 63;
    Qs[r][d] = qt[(size_t)(b * kS + q0 + r) * kD + h * kHD + d];
  }

  float mrow[4], lrow[4], o[4][4];
#pragma unroll
  for (int i = 0; i < 4; ++i) {
    mrow[i] = -INFINITY;
    lrow[i] = 0.f;
#pragma unroll
    for (int j = 0; j < 4; ++j) o[i][j] = 0.f;
  }

  for (int k0 = 0; k0 < kS; k0 += 64) {
    __syncthreads();  // previous tile's P/V reads done
    for (int i = tid; i < 64 * 64; i += 256) {
      int r = i >> 6, d = i & 63;
      size_t base = (size_t)(b * kS + k0 + r) * kD + h * kHD + d;
      KPs[r][d] = kt[base];
      Vs[r][d] = vt[base];
    }
    __syncthreads();

    // scores 4x4 per thread
    float sc[4][4];
#pragma unroll
    for (int i = 0; i < 4; ++i)
#pragma unroll
      for (int j = 0; j < 4; ++j) sc[i][j] = 0.f;
    for (int dd = 0; dd < kHD; dd += 4) {
      float qv[4][4], kv[4][4];
#pragma unroll
      for (int i = 0; i < 4; ++i) {
        float4 t = *(const float4*)&Qs[tq * 4 + i][dd];
        qv[i][0] = t.x; qv[i][1] = t.y; qv[i][2] = t.z; qv[i][3] = t.w;
      }
#pragma unroll
      for (int j = 0; j < 4; ++j) {
        float4 t = *(const float4*)&KPs[tn * 4 + j][dd];
        kv[j][0] = t.x; kv[j][1] = t.y; kv[j][2] = t.z; kv[j][3] = t.w;
      }
#pragma unroll
      for (int i = 0; i < 4; ++i)
#pragma unroll
        for (int j = 0; j < 4; ++j)
#pragma unroll
          for (int c = 0; c < 4; ++c) sc[i][j] += qv[i][c] * kv[j][c];
    }

    // online softmax update
    float ps[4][4], alpha[4];
#pragma unroll
    for (int i = 0; i < 4; ++i) {
      float mx = sc[i][0];
#pragma unroll
      for (int j = 1; j < 4; ++j) mx = fmaxf(mx, sc[i][j]);
      mx *= 0.125f;
      float mx16 = redMax16(mx);
      float mnew = fmaxf(mrow[i], mx16);
      alpha[i] = expf(mrow[i] - mnew);
      mrow[i] = mnew;
      float rs = 0.f;
#pragma unroll
      for (int j = 0; j < 4; ++j) {
        ps[i][j] = expf(sc[i][j] * 0.125f - mnew);
        rs += ps[i][j];
      }
      rs = redSum16(rs);
      lrow[i] = lrow[i] * alpha[i] + rs;
#pragma unroll
      for (int j = 0; j < 4; ++j) o[i][j] *= alpha[i];
    }

    __syncthreads();  // all K reads done before overwriting with P
#pragma unroll
    for (int i = 0; i < 4; ++i) {
      float4 t;
      t.x = ps[i][0]; t.y = ps[i][1]; t.z = ps[i][2]; t.w = ps[i][3];
      *(float4*)&KPs[tq * 4 + i][tn * 4] = t;
    }
    __syncthreads();

    // o += P @ V
    for (int kk = 0; kk < 64; kk += 4) {
      float pv[4][4], vv[4][4];
#pragma unroll
      for (int i = 0; i < 4; ++i) {
        float4 t = *(const float4*)&KPs[tq * 4 + i][kk];
        pv[i][0] = t.x; pv[i][1] = t.y; pv[i][2] = t.z; pv[i][3] = t.w;
      }
#pragma unroll
      for (int c = 0; c < 4; ++c) {
        float4 t = *(const float4*)&Vs[kk + c][tn * 4];
        vv[c][0] = t.x; vv[c][1] = t.y; vv[c][2] = t.z; vv[c][3] = t.w;
      }
#pragma unroll
      for (int i = 0; i < 4; ++i)
#pragma unroll
        for (int j = 0; j < 4; ++j)
#pragma unroll
          for (int c = 0; c < 4; ++c) o[i][j] += pv[i][c] * vv[c][j];
    }
  }

  // finalize: w = o/l ; per-row roundtrip scale over 64 dims; write * ratio2
#pragma unroll
  for (int i = 0; i < 4; ++i) {
    float inv = 1.0f / lrow[i];
    float w[4];
    float pssq = 0.f;
#pragma unroll
    for (int j = 0; j < 4; ++j) { w[j] = o[i][j] * inv; pssq += w[j] * w[j]; }
    float ssq = redSum16(pssq);
    float s3 = roundtrip_scale(sqrtf(ssq));
    float coef = s3 * ratio2;
    int token = b * kS + q0 + tq * 4 + i;
    float4 t;
    t.x = coef * w[0]; t.y = coef * w[1]; t.z = coef * w[2]; t.w = coef * w[3];
    *(float4*)&ao[(size_t)token * kD + h * kHD + tn * 4] = t;
  }
}

// ---------------- roundtrip scale over a row of WIDTH, in place ----------------
template <int WIDTH>
__global__ __launch_bounds__(256) void k_rt_scale(float* __restrict__ p) {
  __shared__ float sred[4];
  constexpr int PER = WIDTH / 256;
  size_t base = (size_t)blockIdx.x * WIDTH;
  float v[PER];
  float ss = 0.f;
#pragma unroll
  for (int i = 0; i < PER; ++i) {
    v[i] = p[base + i * 256 + threadIdx.x];
    ss += v[i] * v[i];
  }
  ss = blockReduceSum256(ss, sred);
  float s = roundtrip_scale(sqrtf(ss));
#pragma unroll
  for (int i = 0; i < PER; ++i) p[base + i * 256 + threadIdx.x] = s * v[i];
}

// ---------------- mobius epilogue: out = mobius_add(xres, expmap0(g*rt(|ot|)*ot)) ----
__global__ __launch_bounds__(256) void k_epilogue(const float* __restrict__ xres,
                                                  const float* __restrict__ ot,
                                                  const float* __restrict__ ada,
                                                  int g_off,
                                                  float* __restrict__ out) {
  __shared__ float sred[4];
  int tok = blockIdx.x;
  int b = tok >> 10;
  const float* xp = xres + (size_t)tok * kD;
  const float* op = ot + (size_t)tok * kD;
  float xv[4], tv[4];
  float ss = 0.f;
#pragma unroll
  for (int i = 0; i < 4; ++i) {
    tv[i] = op[i * 256 + threadIdx.x];
    xv[i] = xp[i * 256 + threadIdx.x];
    ss += tv[i] * tv[i];
  }
  ss = blockReduceSum256(ss, sred);
  float s5 = roundtrip_scale(sqrtf(ss));   // logmap0(expmap0(ot))
  const float* gp = ada + b * 6 * kD + g_off;
  float at2 = 0.f;
#pragma unroll
  for (int i = 0; i < 4; ++i) {
    float a = gp[i * 256 + threadIdx.x] * s5 * tv[i];
    tv[i] = a;
    at2 += a * a;
  }
  at2 = blockReduceSum256(at2, sred);
  float nyraw = sqrtf(at2);
  float sy = expmap0_scale(nyraw);         // y = expmap0(attn_t)
  float ynorm = sy * nyraw;
  float y2 = ynorm * ynorm;
  float x2p = 0.f, xyp = 0.f;
#pragma unroll
  for (int i = 0; i < 4; ++i) {
    float y = sy * tv[i];
    tv[i] = y;
    x2p += xv[i] * xv[i];
    xyp += xv[i] * y;
  }
  float x2 = blockReduceSum256(x2p, sred);
  float xy = blockReduceSum256(xyp, sred);
  float cx = 1.0f + 2.0f * xy + y2;
  float cy = 1.0f - x2;
  float den = fmaxf(1.0f + 2.0f * xy + x2 * y2, EPSF);
  float invden = 1.0f / den;
  float* outp = out + (size_t)tok * kD;
#pragma unroll
  for (int i = 0; i < 4; ++i)
    outp[i * 256 + threadIdx.x] = (cx * xv[i] + cy * tv[i]) * invden;
}

// ---------------------------------------------------------------------------
extern "C" void kernel_launch(void* const* d_in, const int* in_sizes, int n_in,
                              void* d_out, int out_size, void* d_ws, size_t ws_size,
                              hipStream_t stream) {
  const float* x     = (const float*)d_in[0];
  const float* t_emb = (const float*)d_in[1];
  const float* w_q = (const float*)d_in[2];  const float* b_q = (const float*)d_in[3];
  const float* w_k = (const float*)d_in[4];  const float* b_k = (const float*)d_in[5];
  const float* w_v = (const float*)d_in[6];  const float* b_v = (const float*)d_in[7];
  const float* w_o = (const float*)d_in[8];  const float* b_o = (const float*)d_in[9];
  const float* w_f1 = (const float*)d_in[10]; const float* b_f1 = (const float*)d_in[11];
  const float* w_f2 = (const float*)d_in[12]; const float* b_f2 = (const float*)d_in[13];
  const float* w_ada = (const float*)d_in[14]; const float* b_ada = (const float*)d_in[15];
  float* out = (float*)d_out;

  float* ws   = (float*)d_ws;
  float* ada  = ws;                          // 24576
  float* bufA = ada + 6 * kD * kB;           // N*D  (lx / ao / lx2)
  float* bufQ = bufA + (size_t)kN * kD;      // N*D  (q_t / ot / h2)
  float* bufK = bufQ + (size_t)kN * kD;      // N*D  (k_t)
  float* bufV = bufK + (size_t)kN * kD;      // N*D  (v_t / x_mid)
  float* bufH = bufV + (size_t)kN * kD;      // N*FF (h1)

  // beta(n/2, 1/2) ratios (host, double precision)
  double bn = exp(lgamma(512.0) + lgamma(0.5) - lgamma(512.5));
  double bh = exp(lgamma(32.0) + lgamma(0.5) - lgamma(32.5));
  float R1 = (float)(bh / bn);  // BETA_H / BETA_N
  float R2 = (float)(bn / bh);  // BETA_N / BETA_H

  // 1) ada
  k_ada<<<dim3(6 * kD / 256, kB), 256, 0, stream>>>(t_emb, w_ada, b_ada, ada);
  // 2) prenorm (msa): lx -> bufA
  k_prenorm<<<kN, 256, 0, stream>>>(x, ada, 0 * kD, 1 * kD, bufA);
  // 3) q,k,v projections (merged, z=3)
  k_gemm<<<dim3(kD / 128, kN / 128, 3), 256, 0, stream>>>(
      bufA, w_q, w_k, w_v, b_q, b_k, b_v, bufQ, bufK, bufV, kN, kD, kD);
  // 4) head split (in place)
  k_headsplit<<<kN, 256, 0, stream>>>(bufQ, bufK, bufV, R1);
  // 5) attention -> bufA (T tangent, per-head scaled)
  k_attn<<<dim3(kS / 64, kB * kH), 256, 0, stream>>>(bufQ, bufK, bufV, bufA, R2);
  // 6) full-dim roundtrip on T (from_heads expmap0 + plin logmap0)
  k_rt_scale<kD><<<kN, 256, 0, stream>>>(bufA);
  // 7) o projection -> bufQ
  k_gemm<<<dim3(kD / 128, kN / 128, 1), 256, 0, stream>>>(
      bufA, w_o, w_o, w_o, b_o, b_o, b_o, bufQ, bufQ, bufQ, kN, kD, kD);
  // 8) mobius epilogue (msa): x_mid -> bufV
  k_epilogue<<<kN, 256, 0, stream>>>(x, bufQ, ada, 2 * kD, bufV);
  // 9) prenorm (mlp): lx2 -> bufA
  k_prenorm<<<kN, 256, 0, stream>>>(bufV, ada, 3 * kD, 4 * kD, bufA);
  // 10) f1 -> bufH
  k_gemm<<<dim3(kFF / 128, kN / 128, 1), 256, 0, stream>>>(
      bufA, w_f1, w_f1, w_f1, b_f1, b_f1, b_f1, bufH, bufH, bufH, kN, kFF, kD);
  // 11) roundtrip on h1 (width FF)
  k_rt_scale<kFF><<<kN, 256, 0, stream>>>(bufH);
  // 12) f2 -> bufQ
  k_gemm<<<dim3(kD / 128, kN / 128, 1), 256, 0, stream>>>(
      bufH, w_f2, w_f2, w_f2, b_f2, b_f2, b_f2, bufQ, bufQ, bufQ, kN, kD, kFF);
  // 13) mobius epilogue (mlp) -> out
  k_epilogue<<<kN, 256, 0, stream>>>(bufV, bufQ, ada, 5 * kD, out);

  (void)in_sizes; (void)n_in; (void)out_size; (void)ws_size;
}

// Round 2
// 842.170 us; speedup vs baseline: 2.6052x; 2.6052x over previous
//
#include <hip/hip_runtime.h>
#include <cmath>

// ---------------------------------------------------------------------------
// Poincare transformer layer. Round 2: bf16 MFMA GEMMs (m97-style ladder:
// 128x128 tile, BK=32, mfma_f32_16x16x32_bf16, global_load_lds width 16,
// B operand stored N x K bf16). fp32 accumulate, fp32 elementwise/attention.
// Workspace: ~104 MB.
// ---------------------------------------------------------------------------

constexpr int kD  = 1024;
constexpr int kH  = 16;
constexpr int kHD = 64;
constexpr int kFF = 4096;
constexpr int kB  = 4;
constexpr int kS  = 1024;
constexpr int kN  = kB * kS;   // 4096 tokens

#define EPSF 1e-7f
#define MTAF (1.0f - 1e-5f)

typedef unsigned int uint32;
typedef unsigned short ushort16;
typedef __attribute__((ext_vector_type(8))) short short8x;
typedef __attribute__((ext_vector_type(4))) float floatx4;

// ---------------- bf16 helpers ----------------
__device__ __forceinline__ ushort16 f2b(float f) {
  union { float f; uint32 u; } x; x.f = f;
  uint32 r = x.u + 0x7fffu + ((x.u >> 16) & 1u);   // RNE
  return (ushort16)(r >> 16);
}
__device__ __forceinline__ float b2f(ushort16 u) {
  union { uint32 u; float f; } x; x.u = ((uint32)u) << 16;
  return x.f;
}

// ---------------- math helpers ----------------
__device__ __forceinline__ float atanh_clipped(float n) {
  float c = fminf(n, MTAF);
  return 0.5f * logf((1.0f + c) / (1.0f - c));
}
__device__ __forceinline__ float logmap0_scale(float nraw) {
  float n = fmaxf(nraw, EPSF);
  return atanh_clipped(n) / n;
}
__device__ __forceinline__ float expmap0_scale(float nraw) {
  float n = fmaxf(nraw, EPSF);
  return tanhf(n) / n;
}
__device__ __forceinline__ float roundtrip_scale(float nraw) {
  float nu = fmaxf(nraw, EPSF);
  float se = tanhf(nu) / nu;
  float nb = fmaxf(se * nraw, EPSF);
  float sl = atanh_clipped(nb) / nb;
  return sl * se;
}

// ---------------- reductions ----------------
__device__ __forceinline__ float blockReduceSum256(float v, float* s4) {
#pragma unroll
  for (int o = 32; o > 0; o >>= 1) v += __shfl_xor(v, o);
  int wave = threadIdx.x >> 6;
  if ((threadIdx.x & 63) == 0) s4[wave] = v;
  __syncthreads();
  float r = s4[0] + s4[1] + s4[2] + s4[3];
  __syncthreads();
  return r;
}
__device__ __forceinline__ float waveReduceSum64(float v) {
#pragma unroll
  for (int o = 32; o > 0; o >>= 1) v += __shfl_xor(v, o);
  return v;
}
__device__ __forceinline__ float redSum16(float v) {
#pragma unroll
  for (int o = 8; o > 0; o >>= 1) v += __shfl_xor(v, o);
  return v;
}
__device__ __forceinline__ float redMax16(float v) {
#pragma unroll
  for (int o = 8; o > 0; o >>= 1) v = fmaxf(v, __shfl_xor(v, o));
  return v;
}

// ---------------- async global->LDS, 16 bytes/lane ----------------
__device__ __forceinline__ void async16(const void* g, void* l) {
  __builtin_amdgcn_global_load_lds(
      (const __attribute__((address_space(1))) uint32*)g,
      (__attribute__((address_space(3))) uint32*)l, 16, 0, 0);
}

// ---------------- weight transpose + cast: src [K][N] f32 -> dst [N][K] bf16 ----
// grid: (N/64, K/64), 256 threads
__global__ __launch_bounds__(256) void k_transpose_bf16(const float* __restrict__ src,
                                                        ushort16* __restrict__ dst,
                                                        int K, int N) {
  __shared__ float T[64][65];
  int n0 = blockIdx.x * 64, k0 = blockIdx.y * 64;
#pragma unroll
  for (int p = 0; p < 16; ++p) {
    int idx = p * 256 + threadIdx.x;
    int r = idx >> 6, c = idx & 63;
    T[r][c] = src[(size_t)(k0 + r) * N + n0 + c];
  }
  __syncthreads();
#pragma unroll
  for (int p = 0; p < 16; ++p) {
    int idx = p * 256 + threadIdx.x;
    int r = idx >> 6, c = idx & 63;   // r: n-local, c: k-local
    dst[(size_t)(n0 + r) * K + k0 + c] = f2b(T[c][r]);
  }
}

// ---------------- ada = t_emb @ w_ada + b_ada ----------------
__global__ __launch_bounds__(256) void k_ada(const float* __restrict__ t_emb,
                                             const float* __restrict__ w_ada,
                                             const float* __restrict__ b_ada,
                                             float* __restrict__ ada) {
  __shared__ float te[kD];
  int b = blockIdx.y;
  for (int i = threadIdx.x; i < kD; i += 256) te[i] = t_emb[b * kD + i];
  __syncthreads();
  int col = blockIdx.x * 256 + threadIdx.x;
  float acc = b_ada[col];
  for (int k = 0; k < kD; ++k) acc += te[k] * w_ada[(size_t)k * (6 * kD) + col];
  ada[b * 6 * kD + col] = acc;
}

// ---------------- prenorm -> bf16 GEMM input ----------------
__global__ __launch_bounds__(256) void k_prenorm(const float* __restrict__ x,
                                                 const float* __restrict__ ada,
                                                 int sh_off, int sc_off,
                                                 ushort16* __restrict__ out) {
  __shared__ float sred[4];
  int tok = blockIdx.x;
  int b = tok >> 10;
  const float* xp = x + (size_t)tok * kD;
  float xv[4];
  float ss = 0.f;
#pragma unroll
  for (int i = 0; i < 4; ++i) {
    xv[i] = xp[i * 256 + threadIdx.x];
    ss += xv[i] * xv[i];
  }
  ss = blockReduceSum256(ss, sred);
  float sl = logmap0_scale(sqrtf(ss));
  float sum = 0.f;
#pragma unroll
  for (int i = 0; i < 4; ++i) { xv[i] *= sl; sum += xv[i]; }
  sum = blockReduceSum256(sum, sred);
  float mean = sum * (1.0f / kD);
  float vs = 0.f;
#pragma unroll
  for (int i = 0; i < 4; ++i) { xv[i] -= mean; vs += xv[i] * xv[i]; }
  vs = blockReduceSum256(vs, sred);
  float inv = rsqrtf(vs * (1.0f / kD) + 1e-6f);
  const float* shp = ada + b * 6 * kD + sh_off;
  const float* scp = ada + b * 6 * kD + sc_off;
  float uu = 0.f;
#pragma unroll
  for (int i = 0; i < 4; ++i) {
    int d = i * 256 + threadIdx.x;
    float u = xv[i] * inv * (1.0f + scp[d]) + shp[d];
    xv[i] = u;
    uu += u * u;
  }
  uu = blockReduceSum256(uu, sred);
  float s = roundtrip_scale(sqrtf(uu));
  ushort16* op = out + (size_t)tok * kD;
#pragma unroll
  for (int i = 0; i < 4; ++i) op[i * 256 + threadIdx.x] = f2b(s * xv[i]);
}

// ---------------- bf16 MFMA GEMM: C = A @ Bt^T + bias ----------------
// A [M][K] bf16, Bt [N][K] bf16, C [M][N] f32 (or bf16 if OUT_BF16).
// 128x128 tile, BK=32, 256 threads = 4 waves, each wave 64x64 via 4x4 MFMA frags.
template <int OUT_BF16>
__global__ __launch_bounds__(256) void k_gemm_bf16(
    const ushort16* __restrict__ A,
    const ushort16* __restrict__ Bt0, const ushort16* __restrict__ Bt1,
    const ushort16* __restrict__ Bt2,
    const float* __restrict__ bias0, const float* __restrict__ bias1,
    const float* __restrict__ bias2,
    void* __restrict__ C0, void* __restrict__ C1, void* __restrict__ C2,
    int M, int N, int K) {
  const ushort16* Bt = (blockIdx.z == 0) ? Bt0 : ((blockIdx.z == 1) ? Bt1 : Bt2);
  const float* bias = (blockIdx.z == 0) ? bias0 : ((blockIdx.z == 1) ? bias1 : bias2);
  void* C = (blockIdx.z == 0) ? C0 : ((blockIdx.z == 1) ? C1 : C2);

  __shared__ __align__(16) ushort16 As[128 * 32];
  __shared__ __align__(16) ushort16 Bs[128 * 32];

  int tid = threadIdx.x;
  int lane = tid & 63;
  int wave = tid >> 6;
  int wm = (wave >> 1) * 64, wn = (wave & 1) * 64;
  int row0 = blockIdx.y * 128, col0 = blockIdx.x * 128;

  // staging coords: element e = (chunk*256 + tid) * 8 within 128x32 tile
  int e0 = tid * 8;
  int ar0 = e0 >> 5, ac0 = e0 & 31;
  int e1 = e0 + 2048;
  int ar1 = e1 >> 5, ac1 = e1 & 31;
  const ushort16* Ag = A + (size_t)row0 * K;
  const ushort16* Bg = Bt + (size_t)col0 * K;

  floatx4 acc[4][4];
#pragma unroll
  for (int i = 0; i < 4; ++i)
#pragma unroll
    for (int j = 0; j < 4; ++j) acc[i][j] = (floatx4)0.f;

  for (int k0 = 0; k0 < K; k0 += 32) {
    async16(Ag + (size_t)ar0 * K + k0 + ac0, As + e0);
    async16(Ag + (size_t)ar1 * K + k0 + ac1, As + e1);
    async16(Bg + (size_t)ar0 * K + k0 + ac0, Bs + e0);
    async16(Bg + (size_t)ar1 * K + k0 + ac1, Bs + e1);
    __syncthreads();   // drains vmcnt: staged data visible

    short8x a[4], b[4];
#pragma unroll
    for (int i = 0; i < 4; ++i) {
      a[i] = *(const short8x*)&As[(wm + i * 16 + (lane & 15)) * 32 + (lane >> 4) * 8];
      b[i] = *(const short8x*)&Bs[(wn + i * 16 + (lane & 15)) * 32 + (lane >> 4) * 8];
    }
#pragma unroll
    for (int i = 0; i < 4; ++i)
#pragma unroll
      for (int j = 0; j < 4; ++j)
        acc[i][j] = __builtin_amdgcn_mfma_f32_16x16x32_bf16(a[i], b[j], acc[i][j], 0, 0, 0);
    __syncthreads();   // LDS reads done before next stage overwrites
  }

  // epilogue: C/D layout col=lane&15, row=(lane>>4)*4+reg
  float bv[4];
#pragma unroll
  for (int j = 0; j < 4; ++j) bv[j] = bias[col0 + wn + j * 16 + (lane & 15)];
  int rowq = (lane >> 4) * 4;
#pragma unroll
  for (int i = 0; i < 4; ++i) {
    int rbase = row0 + wm + i * 16 + rowq;
#pragma unroll
    for (int j = 0; j < 4; ++j) {
      int c = col0 + wn + j * 16 + (lane & 15);
#pragma unroll
      for (int r = 0; r < 4; ++r) {
        float v = acc[i][j][r] + bv[j];
        if (OUT_BF16)
          ((ushort16*)C)[(size_t)(rbase + r) * N + c] = f2b(v);
        else
          ((float*)C)[(size_t)(rbase + r) * N + c] = v;
      }
    }
  }
}

// ---------------- head split (fp32, in place) ----------------
__global__ __launch_bounds__(256) void k_headsplit(float* __restrict__ q,
                                                   float* __restrict__ k,
                                                   float* __restrict__ v,
                                                   float ratio) {
  __shared__ float sh[16];
  int tok = blockIdx.x;
  int tid = threadIdx.x, wave = tid >> 6;
  float* ptrs[3] = {q, k, v};
#pragma unroll
  for (int t = 0; t < 3; ++t) {
    float* p = ptrs[t] + (size_t)tok * kD;
    float val[4], hs[4];
#pragma unroll
    for (int i = 0; i < 4; ++i) {
      val[i] = p[i * 256 + tid];
      hs[i] = waveReduceSum64(val[i] * val[i]);
    }
    if ((tid & 63) == 0) {
#pragma unroll
      for (int i = 0; i < 4; ++i) sh[i * 4 + wave] = hs[i];
    }
    __syncthreads();
    float tot = 0.f;
#pragma unroll
    for (int j = 0; j < 16; ++j) tot += sh[j];
    float s1 = roundtrip_scale(sqrtf(tot));
    float c = s1 * ratio;
#pragma unroll
    for (int i = 0; i < 4; ++i) {
      float m = c * sqrtf(hs[i]);
      float s2 = roundtrip_scale(m);
      p[i * 256 + tid] = c * s2 * val[i];
    }
    __syncthreads();
  }
}

// ---------------- flash attention; writes result IN PLACE into qt ----------------
// Safe: block (b,h,q0) writes exactly the qt region only it reads, after reading.
__global__ __launch_bounds__(256) void k_attn(float* __restrict__ qt,
                                              const float* __restrict__ kt,
                                              const float* __restrict__ vt,
                                              float ratio2) {
  __shared__ __align__(16) float Qs[64][68];
  __shared__ __align__(16) float KPs[64][68];
  __shared__ __align__(16) float Vs[64][68];
  int bh = blockIdx.y;
  int b = bh >> 4, h = bh & 15;
  int q0 = blockIdx.x * 64;
  int tid = threadIdx.x;
  int tq = tid >> 4, tn = tid & 15;

  for (int i = tid; i < 64 * 64; i += 256) {
    int r = i >> 6, d = i & 63;
    Qs[r][d] = qt[(size_t)(b * kS + q0 + r) * kD + h * kHD + d];
  }

  float mrow[4], lrow[4], o[4][4];
#pragma unroll
  for (int i = 0; i < 4; ++i) {
    mrow[i] = -INFINITY;
    lrow[i] = 0.f;
#pragma unroll
    for (int j = 0; j < 4; ++j) o[i][j] = 0.f;
  }

  for (int k0 = 0; k0 < kS; k0 += 64) {
    __syncthreads();
    for (int i = tid; i < 64 * 64; i += 256) {
      int r = i >> 6, d = i & 63;
      size_t base = (size_t)(b * kS + k0 + r) * kD + h * kHD + d;
      KPs[r][d] = kt[base];
      Vs[r][d] = vt[base];
    }
    __syncthreads();

    float sc[4][4];
#pragma unroll
    for (int i = 0; i < 4; ++i)
#pragma unroll
      for (int j = 0; j < 4; ++j) sc[i][j] = 0.f;
    for (int dd = 0; dd < kHD; dd += 4) {
      float qv[4][4], kv[4][4];
#pragma unroll
      for (int i = 0; i < 4; ++i) {
        float4 t = *(const float4*)&Qs[tq * 4 + i][dd];
        qv[i][0] = t.x; qv[i][1] = t.y; qv[i][2] = t.z; qv[i][3] = t.w;
      }
#pragma unroll
      for (int j = 0; j < 4; ++j) {
        float4 t = *(const float4*)&KPs[tn * 4 + j][dd];
        kv[j][0] = t.x; kv[j][1] = t.y; kv[j][2] = t.z; kv[j][3] = t.w;
      }
#pragma unroll
      for (int i = 0; i < 4; ++i)
#pragma unroll
        for (int j = 0; j < 4; ++j)
#pragma unroll
          for (int c = 0; c < 4; ++c) sc[i][j] += qv[i][c] * kv[j][c];
    }

    float ps[4][4], alpha[4];
#pragma unroll
    for (int i = 0; i < 4; ++i) {
      float mx = sc[i][0];
#pragma unroll
      for (int j = 1; j < 4; ++j) mx = fmaxf(mx, sc[i][j]);
      mx *= 0.125f;
      float mx16 = redMax16(mx);
      float mnew = fmaxf(mrow[i], mx16);
      alpha[i] = expf(mrow[i] - mnew);
      mrow[i] = mnew;
      float rs = 0.f;
#pragma unroll
      for (int j = 0; j < 4; ++j) {
        ps[i][j] = expf(sc[i][j] * 0.125f - mnew);
        rs += ps[i][j];
      }
      rs = redSum16(rs);
      lrow[i] = lrow[i] * alpha[i] + rs;
#pragma unroll
      for (int j = 0; j < 4; ++j) o[i][j] *= alpha[i];
    }

    __syncthreads();
#pragma unroll
    for (int i = 0; i < 4; ++i) {
      float4 t;
      t.x = ps[i][0]; t.y = ps[i][1]; t.z = ps[i][2]; t.w = ps[i][3];
      *(float4*)&KPs[tq * 4 + i][tn * 4] = t;
    }
    __syncthreads();

    for (int kk = 0; kk < 64; kk += 4) {
      float pv[4][4], vv[4][4];
#pragma unroll
      for (int i = 0; i < 4; ++i) {
        float4 t = *(const float4*)&KPs[tq * 4 + i][kk];
        pv[i][0] = t.x; pv[i][1] = t.y; pv[i][2] = t.z; pv[i][3] = t.w;
      }
#pragma unroll
      for (int c = 0; c < 4; ++c) {
        float4 t = *(const float4*)&Vs[kk + c][tn * 4];
        vv[c][0] = t.x; vv[c][1] = t.y; vv[c][2] = t.z; vv[c][3] = t.w;
      }
#pragma unroll
      for (int i = 0; i < 4; ++i)
#pragma unroll
        for (int j = 0; j < 4; ++j)
#pragma unroll
          for (int c = 0; c < 4; ++c) o[i][j] += pv[i][c] * vv[c][j];
    }
  }

#pragma unroll
  for (int i = 0; i < 4; ++i) {
    float inv = 1.0f / lrow[i];
    float w[4];
    float pssq = 0.f;
#pragma unroll
    for (int j = 0; j < 4; ++j) { w[j] = o[i][j] * inv; pssq += w[j] * w[j]; }
    float ssq = redSum16(pssq);
    float s3 = roundtrip_scale(sqrtf(ssq));
    float coef = s3 * ratio2;
    int token = b * kS + q0 + tq * 4 + i;
    float4 t;
    t.x = coef * w[0]; t.y = coef * w[1]; t.z = coef * w[2]; t.w = coef * w[3];
    *(float4*)&qt[(size_t)token * kD + h * kHD + tn * 4] = t;
  }
}

// ---------------- roundtrip scale, fp32 in -> bf16 out ----------------
template <int WIDTH>
__global__ __launch_bounds__(256) void k_rt_scale_f2b(const float* __restrict__ p,
                                                      ushort16* __restrict__ out) {
  __shared__ float sred[4];
  constexpr int PER = WIDTH / 256;
  size_t base = (size_t)blockIdx.x * WIDTH;
  float v[PER];
  float ss = 0.f;
#pragma unroll
  for (int i = 0; i < PER; ++i) {
    v[i] = p[base + i * 256 + threadIdx.x];
    ss += v[i] * v[i];
  }
  ss = blockReduceSum256(ss, sred);
  float s = roundtrip_scale(sqrtf(ss));
#pragma unroll
  for (int i = 0; i < PER; ++i) out[base + i * 256 + threadIdx.x] = f2b(s * v[i]);
}

// ---------------- roundtrip scale, bf16 in/out (in place) ----------------
template <int WIDTH>
__global__ __launch_bounds__(256) void k_rt_scale_b2b(ushort16* __restrict__ p) {
  __shared__ float sred[4];
  constexpr int PER = WIDTH / 256;
  size_t base = (size_t)blockIdx.x * WIDTH;
  float v[PER];
  float ss = 0.f;
#pragma unroll
  for (int i = 0; i < PER; ++i) {
    v[i] = b2f(p[base + i * 256 + threadIdx.x]);
    ss += v[i] * v[i];
  }
  ss = blockReduceSum256(ss, sred);
  float s = roundtrip_scale(sqrtf(ss));
#pragma unroll
  for (int i = 0; i < PER; ++i) p[base + i * 256 + threadIdx.x] = f2b(s * v[i]);
}

// ---------------- mobius epilogue ----------------
__global__ __launch_bounds__(256) void k_epilogue(const float* __restrict__ xres,
                                                  const float* __restrict__ ot,
                                                  const float* __restrict__ ada,
                                                  int g_off,
                                                  float* __restrict__ out) {
  __shared__ float sred[4];
  int tok = blockIdx.x;
  int b = tok >> 10;
  const float* xp = xres + (size_t)tok * kD;
  const float* op = ot + (size_t)tok * kD;
  float xv[4], tv[4];
  float ss = 0.f;
#pragma unroll
  for (int i = 0; i < 4; ++i) {
    tv[i] = op[i * 256 + threadIdx.x];
    xv[i] = xp[i * 256 + threadIdx.x];
    ss += tv[i] * tv[i];
  }
  ss = blockReduceSum256(ss, sred);
  float s5 = roundtrip_scale(sqrtf(ss));
  const float* gp = ada + b * 6 * kD + g_off;
  float at2 = 0.f;
#pragma unroll
  for (int i = 0; i < 4; ++i) {
    float a = gp[i * 256 + threadIdx.x] * s5 * tv[i];
    tv[i] = a;
    at2 += a * a;
  }
  at2 = blockReduceSum256(at2, sred);
  float nyraw = sqrtf(at2);
  float sy = expmap0_scale(nyraw);
  float ynorm = sy * nyraw;
  float y2 = ynorm * ynorm;
  float x2p = 0.f, xyp = 0.f;
#pragma unroll
  for (int i = 0; i < 4; ++i) {
    float y = sy * tv[i];
    tv[i] = y;
    x2p += xv[i] * xv[i];
    xyp += xv[i] * y;
  }
  float x2 = blockReduceSum256(x2p, sred);
  float xy = blockReduceSum256(xyp, sred);
  float cx = 1.0f + 2.0f * xy + y2;
  float cy = 1.0f - x2;
  float den = fmaxf(1.0f + 2.0f * xy + x2 * y2, EPSF);
  float invden = 1.0f / den;
  float* outp = out + (size_t)tok * kD;
#pragma unroll
  for (int i = 0; i < 4; ++i)
    outp[i * 256 + threadIdx.x] = (cx * xv[i] + cy * tv[i]) * invden;
}

// ---------------------------------------------------------------------------
extern "C" void kernel_launch(void* const* d_in, const int* in_sizes, int n_in,
                              void* d_out, int out_size, void* d_ws, size_t ws_size,
                              hipStream_t stream) {
  const float* x     = (const float*)d_in[0];
  const float* t_emb = (const float*)d_in[1];
  const float* w_q = (const float*)d_in[2];  const float* b_q = (const float*)d_in[3];
  const float* w_k = (const float*)d_in[4];  const float* b_k = (const float*)d_in[5];
  const float* w_v = (const float*)d_in[6];  const float* b_v = (const float*)d_in[7];
  const float* w_o = (const float*)d_in[8];  const float* b_o = (const float*)d_in[9];
  const float* w_f1 = (const float*)d_in[10]; const float* b_f1 = (const float*)d_in[11];
  const float* w_f2 = (const float*)d_in[12]; const float* b_f2 = (const float*)d_in[13];
  const float* w_ada = (const float*)d_in[14]; const float* b_ada = (const float*)d_in[15];
  float* out = (float*)d_out;

  constexpr size_t ND = (size_t)kN * kD;    // 4 M
  constexpr size_t NF = (size_t)kN * kFF;   // 16 M
  constexpr size_t DD = (size_t)kD * kD;    // 1 M

  float* ws   = (float*)d_ws;
  float* ada  = ws;                 // 24576 f32
  float* qt   = ada + 6 * kD * kB;  // ND f32  (q_t -> attn out, -> f2 out)
  float* kt   = qt + ND;            // ND f32  (k_t -> o-gemm out)
  float* vt   = kt + ND;            // ND f32  (v_t -> x_mid)
  ushort16* actA = (ushort16*)(vt + ND);  // ND bf16 (lx / rt(ao) / lx2)
  ushort16* actB = actA + ND;             // NF bf16 (h1)
  ushort16* wqT  = actB + NF;             // DD bf16 each
  ushort16* wkT  = wqT + DD;
  ushort16* wvT  = wkT + DD;
  ushort16* woT  = wvT + DD;
  ushort16* wf1T = woT + DD;              // FF*D bf16
  ushort16* wf2T = wf1T + (size_t)kD * kFF;

  double bn = exp(lgamma(512.0) + lgamma(0.5) - lgamma(512.5));
  double bh = exp(lgamma(32.0) + lgamma(0.5) - lgamma(32.5));
  float R1 = (float)(bh / bn);
  float R2 = (float)(bn / bh);

  // 0) weight transpose + cast to bf16 [N][K]
  k_transpose_bf16<<<dim3(16, 16), 256, 0, stream>>>(w_q, wqT, kD, kD);
  k_transpose_bf16<<<dim3(16, 16), 256, 0, stream>>>(w_k, wkT, kD, kD);
  k_transpose_bf16<<<dim3(16, 16), 256, 0, stream>>>(w_v, wvT, kD, kD);
  k_transpose_bf16<<<dim3(16, 16), 256, 0, stream>>>(w_o, woT, kD, kD);
  k_transpose_bf16<<<dim3(64, 16), 256, 0, stream>>>(w_f1, wf1T, kD, kFF);
  k_transpose_bf16<<<dim3(16, 64), 256, 0, stream>>>(w_f2, wf2T, kFF, kD);
  // 1) ada
  k_ada<<<dim3(6 * kD / 256, kB), 256, 0, stream>>>(t_emb, w_ada, b_ada, ada);
  // 2) prenorm (msa): lx -> actA (bf16)
  k_prenorm<<<kN, 256, 0, stream>>>(x, ada, 0 * kD, 1 * kD, actA);
  // 3) q,k,v projections (merged, z=3) -> qt/kt/vt f32
  k_gemm_bf16<0><<<dim3(kD / 128, kN / 128, 3), 256, 0, stream>>>(
      actA, wqT, wkT, wvT, b_q, b_k, b_v, qt, kt, vt, kN, kD, kD);
  // 4) head split (in place)
  k_headsplit<<<kN, 256, 0, stream>>>(qt, kt, vt, R1);
  // 5) attention: writes tangent output in place into qt
  k_attn<<<dim3(kS / 64, kB * kH), 256, 0, stream>>>(qt, kt, vt, R2);
  // 6) full-dim roundtrip -> actA (bf16)
  k_rt_scale_f2b<kD><<<kN, 256, 0, stream>>>(qt, actA);
  // 7) o projection -> kt f32
  k_gemm_bf16<0><<<dim3(kD / 128, kN / 128, 1), 256, 0, stream>>>(
      actA, woT, woT, woT, b_o, b_o, b_o, kt, kt, kt, kN, kD, kD);
  // 8) mobius epilogue (msa): x_mid -> vt
  k_epilogue<<<kN, 256, 0, stream>>>(x, kt, ada, 2 * kD, vt);
  // 9) prenorm (mlp): lx2 -> actA (bf16)
  k_prenorm<<<kN, 256, 0, stream>>>(vt, ada, 3 * kD, 4 * kD, actA);
  // 10) f1 -> actB (bf16 direct)
  k_gemm_bf16<1><<<dim3(kFF / 128, kN / 128, 1), 256, 0, stream>>>(
      actA, wf1T, wf1T, wf1T, b_f1, b_f1, b_f1, actB, actB, actB, kN, kFF, kD);
  // 11) roundtrip on h1 (bf16 in place)
  k_rt_scale_b2b<kFF><<<kN, 256, 0, stream>>>(actB);
  // 12) f2 -> qt f32
  k_gemm_bf16<0><<<dim3(kD / 128, kN / 128, 1), 256, 0, stream>>>(
      actB, wf2T, wf2T, wf2T, b_f2, b_f2, b_f2, qt, qt, qt, kN, kD, kFF);
  // 13) mobius epilogue (mlp) -> out
  k_epilogue<<<kN, 256, 0, stream>>>(vt, qt, ada, 5 * kD, out);

  (void)in_sizes; (void)n_in; (void)out_size; (void)ws_size;
}

// Round 3
// 581.067 us; speedup vs baseline: 3.7758x; 1.4494x over previous
//
#include <hip/hip_runtime.h>
#include <cmath>

// ---------------------------------------------------------------------------
// Poincare transformer layer. Round 3: bf16 MFMA GEMMs + bf16 MFMA flash
// attention. fp32 accumulate everywhere, fp32 elementwise.
// Workspace: 134,316,032 B (= round-1 proven usage).
// ---------------------------------------------------------------------------

constexpr int kD  = 1024;
constexpr int kH  = 16;
constexpr int kHD = 64;
constexpr int kFF = 4096;
constexpr int kB  = 4;
constexpr int kS  = 1024;
constexpr int kN  = kB * kS;   // 4096 tokens

#define EPSF 1e-7f
#define MTAF (1.0f - 1e-5f)

typedef unsigned int uint32;
typedef unsigned short ushort16;
typedef __attribute__((ext_vector_type(8))) short short8x;
typedef __attribute__((ext_vector_type(4))) float floatx4;

// ---------------- bf16 helpers ----------------
__device__ __forceinline__ ushort16 f2b(float f) {
  union { float f; uint32 u; } x; x.f = f;
  uint32 r = x.u + 0x7fffu + ((x.u >> 16) & 1u);   // RNE
  return (ushort16)(r >> 16);
}
__device__ __forceinline__ float b2f(ushort16 u) {
  union { uint32 u; float f; } x; x.u = ((uint32)u) << 16;
  return x.f;
}

// ---------------- math helpers ----------------
__device__ __forceinline__ float atanh_clipped(float n) {
  float c = fminf(n, MTAF);
  return 0.5f * logf((1.0f + c) / (1.0f - c));
}
__device__ __forceinline__ float logmap0_scale(float nraw) {
  float n = fmaxf(nraw, EPSF);
  return atanh_clipped(n) / n;
}
__device__ __forceinline__ float expmap0_scale(float nraw) {
  float n = fmaxf(nraw, EPSF);
  return tanhf(n) / n;
}
__device__ __forceinline__ float roundtrip_scale(float nraw) {
  float nu = fmaxf(nraw, EPSF);
  float se = tanhf(nu) / nu;
  float nb = fmaxf(se * nraw, EPSF);
  float sl = atanh_clipped(nb) / nb;
  return sl * se;
}

// ---------------- reductions ----------------
__device__ __forceinline__ float blockReduceSum256(float v, float* s4) {
#pragma unroll
  for (int o = 32; o > 0; o >>= 1) v += __shfl_xor(v, o);
  int wave = threadIdx.x >> 6;
  if ((threadIdx.x & 63) == 0) s4[wave] = v;
  __syncthreads();
  float r = s4[0] + s4[1] + s4[2] + s4[3];
  __syncthreads();
  return r;
}
__device__ __forceinline__ float waveReduceSum64(float v) {
#pragma unroll
  for (int o = 32; o > 0; o >>= 1) v += __shfl_xor(v, o);
  return v;
}
__device__ __forceinline__ float redSum16(float v) {
#pragma unroll
  for (int o = 8; o > 0; o >>= 1) v += __shfl_xor(v, o);
  return v;
}
__device__ __forceinline__ float redMax16(float v) {
#pragma unroll
  for (int o = 8; o > 0; o >>= 1) v = fmaxf(v, __shfl_xor(v, o));
  return v;
}

// ---------------- async global->LDS, 16 bytes/lane ----------------
__device__ __forceinline__ void async16(const void* g, void* l) {
  __builtin_amdgcn_global_load_lds(
      (const __attribute__((address_space(1))) uint32*)g,
      (__attribute__((address_space(3))) uint32*)l, 16, 0, 0);
}

// ---------------- weight transpose + cast: src [K][N] f32 -> dst [N][K] bf16 ----
__global__ __launch_bounds__(256) void k_transpose_bf16(const float* __restrict__ src,
                                                        ushort16* __restrict__ dst,
                                                        int K, int N) {
  __shared__ float T[64][65];
  int n0 = blockIdx.x * 64, k0 = blockIdx.y * 64;
#pragma unroll
  for (int p = 0; p < 16; ++p) {
    int idx = p * 256 + threadIdx.x;
    int r = idx >> 6, c = idx & 63;
    T[r][c] = src[(size_t)(k0 + r) * N + n0 + c];
  }
  __syncthreads();
#pragma unroll
  for (int p = 0; p < 16; ++p) {
    int idx = p * 256 + threadIdx.x;
    int r = idx >> 6, c = idx & 63;   // r: n-local, c: k-local
    dst[(size_t)(n0 + r) * K + k0 + c] = f2b(T[c][r]);
  }
}

// ---------------- ada = t_emb @ w_ada + b_ada ----------------
__global__ __launch_bounds__(256) void k_ada(const float* __restrict__ t_emb,
                                             const float* __restrict__ w_ada,
                                             const float* __restrict__ b_ada,
                                             float* __restrict__ ada) {
  __shared__ float te[kD];
  int b = blockIdx.y;
  for (int i = threadIdx.x; i < kD; i += 256) te[i] = t_emb[b * kD + i];
  __syncthreads();
  int col = blockIdx.x * 256 + threadIdx.x;
  float acc = b_ada[col];
  for (int k = 0; k < kD; ++k) acc += te[k] * w_ada[(size_t)k * (6 * kD) + col];
  ada[b * 6 * kD + col] = acc;
}

// ---------------- prenorm -> bf16 GEMM input ----------------
__global__ __launch_bounds__(256) void k_prenorm(const float* __restrict__ x,
                                                 const float* __restrict__ ada,
                                                 int sh_off, int sc_off,
                                                 ushort16* __restrict__ out) {
  __shared__ float sred[4];
  int tok = blockIdx.x;
  int b = tok >> 10;
  const float* xp = x + (size_t)tok * kD;
  float xv[4];
  float ss = 0.f;
#pragma unroll
  for (int i = 0; i < 4; ++i) {
    xv[i] = xp[i * 256 + threadIdx.x];
    ss += xv[i] * xv[i];
  }
  ss = blockReduceSum256(ss, sred);
  float sl = logmap0_scale(sqrtf(ss));
  float sum = 0.f;
#pragma unroll
  for (int i = 0; i < 4; ++i) { xv[i] *= sl; sum += xv[i]; }
  sum = blockReduceSum256(sum, sred);
  float mean = sum * (1.0f / kD);
  float vs = 0.f;
#pragma unroll
  for (int i = 0; i < 4; ++i) { xv[i] -= mean; vs += xv[i] * xv[i]; }
  vs = blockReduceSum256(vs, sred);
  float inv = rsqrtf(vs * (1.0f / kD) + 1e-6f);
  const float* shp = ada + b * 6 * kD + sh_off;
  const float* scp = ada + b * 6 * kD + sc_off;
  float uu = 0.f;
#pragma unroll
  for (int i = 0; i < 4; ++i) {
    int d = i * 256 + threadIdx.x;
    float u = xv[i] * inv * (1.0f + scp[d]) + shp[d];
    xv[i] = u;
    uu += u * u;
  }
  uu = blockReduceSum256(uu, sred);
  float s = roundtrip_scale(sqrtf(uu));
  ushort16* op = out + (size_t)tok * kD;
#pragma unroll
  for (int i = 0; i < 4; ++i) op[i * 256 + threadIdx.x] = f2b(s * xv[i]);
}

// ---------------- bf16 MFMA GEMM: C = A @ Bt^T + bias ----------------
template <int OUT_BF16>
__global__ __launch_bounds__(256) void k_gemm_bf16(
    const ushort16* __restrict__ A,
    const ushort16* __restrict__ Bt0, const ushort16* __restrict__ Bt1,
    const ushort16* __restrict__ Bt2,
    const float* __restrict__ bias0, const float* __restrict__ bias1,
    const float* __restrict__ bias2,
    void* __restrict__ C0, void* __restrict__ C1, void* __restrict__ C2,
    int M, int N, int K) {
  const ushort16* Bt = (blockIdx.z == 0) ? Bt0 : ((blockIdx.z == 1) ? Bt1 : Bt2);
  const float* bias = (blockIdx.z == 0) ? bias0 : ((blockIdx.z == 1) ? bias1 : bias2);
  void* C = (blockIdx.z == 0) ? C0 : ((blockIdx.z == 1) ? C1 : C2);

  __shared__ __align__(16) ushort16 As[128 * 32];
  __shared__ __align__(16) ushort16 Bs[128 * 32];

  int tid = threadIdx.x;
  int lane = tid & 63;
  int wave = tid >> 6;
  int wm = (wave >> 1) * 64, wn = (wave & 1) * 64;
  int row0 = blockIdx.y * 128, col0 = blockIdx.x * 128;

  int e0 = tid * 8;
  int ar0 = e0 >> 5, ac0 = e0 & 31;
  int e1 = e0 + 2048;
  int ar1 = e1 >> 5, ac1 = e1 & 31;
  const ushort16* Ag = A + (size_t)row0 * K;
  const ushort16* Bg = Bt + (size_t)col0 * K;

  floatx4 acc[4][4];
#pragma unroll
  for (int i = 0; i < 4; ++i)
#pragma unroll
    for (int j = 0; j < 4; ++j) acc[i][j] = (floatx4)0.f;

  for (int k0 = 0; k0 < K; k0 += 32) {
    async16(Ag + (size_t)ar0 * K + k0 + ac0, As + e0);
    async16(Ag + (size_t)ar1 * K + k0 + ac1, As + e1);
    async16(Bg + (size_t)ar0 * K + k0 + ac0, Bs + e0);
    async16(Bg + (size_t)ar1 * K + k0 + ac1, Bs + e1);
    __syncthreads();

    short8x a[4], b[4];
#pragma unroll
    for (int i = 0; i < 4; ++i) {
      a[i] = *(const short8x*)&As[(wm + i * 16 + (lane & 15)) * 32 + (lane >> 4) * 8];
      b[i] = *(const short8x*)&Bs[(wn + i * 16 + (lane & 15)) * 32 + (lane >> 4) * 8];
    }
#pragma unroll
    for (int i = 0; i < 4; ++i)
#pragma unroll
      for (int j = 0; j < 4; ++j)
        acc[i][j] = __builtin_amdgcn_mfma_f32_16x16x32_bf16(a[i], b[j], acc[i][j], 0, 0, 0);
    __syncthreads();
  }

  float bv[4];
#pragma unroll
  for (int j = 0; j < 4; ++j) bv[j] = bias[col0 + wn + j * 16 + (lane & 15)];
  int rowq = (lane >> 4) * 4;
#pragma unroll
  for (int i = 0; i < 4; ++i) {
    int rbase = row0 + wm + i * 16 + rowq;
#pragma unroll
    for (int j = 0; j < 4; ++j) {
      int c = col0 + wn + j * 16 + (lane & 15);
#pragma unroll
      for (int r = 0; r < 4; ++r) {
        float v = acc[i][j][r] + bv[j];
        if (OUT_BF16)
          ((ushort16*)C)[(size_t)(rbase + r) * N + c] = f2b(v);
        else
          ((float*)C)[(size_t)(rbase + r) * N + c] = v;
      }
    }
  }
}

// ---------------- head split: f32 qkv -> bf16 qb (pre-scaled 1/8), bf16 kb,
// ---------------- f32 vt in place. Folds _to_heads + logmap0 scales. ----------------
__global__ __launch_bounds__(256) void k_headsplit2(const float* __restrict__ qs,
                                                    const float* __restrict__ ks,
                                                    float* __restrict__ vs,
                                                    ushort16* __restrict__ qb,
                                                    ushort16* __restrict__ kb,
                                                    float ratio) {
  __shared__ float sh[16];
  int tok = blockIdx.x;
  int tid = threadIdx.x, wave = tid >> 6;
#pragma unroll
  for (int t = 0; t < 3; ++t) {
    const float* p = (t == 0 ? qs : (t == 1 ? ks : (const float*)vs)) + (size_t)tok * kD;
    float val[4], hs[4];
#pragma unroll
    for (int i = 0; i < 4; ++i) {
      val[i] = p[i * 256 + tid];
      hs[i] = waveReduceSum64(val[i] * val[i]);  // head (i*4 + wave) sumsq
    }
    if ((tid & 63) == 0) {
#pragma unroll
      for (int i = 0; i < 4; ++i) sh[i * 4 + wave] = hs[i];
    }
    __syncthreads();
    float tot = 0.f;
#pragma unroll
    for (int j = 0; j < 16; ++j) tot += sh[j];
    float s1 = roundtrip_scale(sqrtf(tot));
    float c = s1 * ratio;
#pragma unroll
    for (int i = 0; i < 4; ++i) {
      float m = c * sqrtf(hs[i]);
      float s2 = roundtrip_scale(m);
      float ov = c * s2 * val[i];
      size_t idx = (size_t)tok * kD + i * 256 + tid;
      if (t == 0) qb[idx] = f2b(0.125f * ov);       // fold 1/sqrt(HD)
      else if (t == 1) kb[idx] = f2b(ov);
      else vs[idx] = ov;
    }
    __syncthreads();
  }
}

// ---------------- V transpose: vt f32 [N][D] -> vT bf16 [B*H][64][S] ----------------
__global__ __launch_bounds__(256) void k_vtrans(const float* __restrict__ vt,
                                                ushort16* __restrict__ vT) {
  __shared__ float T[64][65];
  int bh = blockIdx.y, b = bh >> 4, h = bh & 15;
  int s0 = blockIdx.x * 64;
  int tid = threadIdx.x;
#pragma unroll
  for (int p = 0; p < 16; ++p) {
    int idx = p * 256 + tid;
    int r = idx >> 6, d = idx & 63;
    T[r][d] = vt[(size_t)(b * kS + s0 + r) * kD + h * kHD + d];
  }
  __syncthreads();
#pragma unroll
  for (int p = 0; p < 16; ++p) {
    int idx = p * 256 + tid;
    int d = idx >> 6, c = idx & 63;
    vT[((size_t)bh * kHD + d) * kS + s0 + c] = f2b(T[c][d]);
  }
}

// ---------------- MFMA flash attention ----------------
// grid (S/128, B*H), 256 threads = 4 waves; wave owns 32 q-rows (2 x 16).
// qb: bf16 [N][D] pre-scaled by 1/8. kb: bf16 [N][D]. vT: bf16 [B*H][64][S].
// outp: f32 [N][D] = rt(|w|)*ratio2*w per head-row (tangent, pre-concat-rt).
__global__ __launch_bounds__(256) void k_attn_mfma(const ushort16* __restrict__ qb,
                                                   const ushort16* __restrict__ kb,
                                                   const ushort16* __restrict__ vT,
                                                   float* __restrict__ outp,
                                                   float ratio2) {
  __shared__ __align__(16) ushort16 Ks[2 * 128 * 32];   // [ksub(d)][key][32]
  __shared__ __align__(16) ushort16 Vs[4 * 64 * 32];    // [ssub][d][32]
  __shared__ __align__(16) ushort16 Ps[4 * 4 * 16 * 32];// [wave][ksub(s)][row16][32]
  int bh = blockIdx.y, b = bh >> 4, h = bh & 15;
  int q0 = blockIdx.x * 128;
  int tid = threadIdx.x, lane = tid & 63, wave = tid >> 6;
  int c16 = lane & 15, quad = lane >> 4;
  int wq = wave * 32;

  // Q fragments (A layout): rows wq..wq+31, 64 d
  short8x a_q[2][2];
#pragma unroll
  for (int i = 0; i < 2; ++i)
#pragma unroll
    for (int kk = 0; kk < 2; ++kk)
      a_q[i][kk] = *(const short8x*)&qb[(size_t)(b * kS + q0 + wq + i * 16 + c16) * kD +
                                        h * kHD + kk * 32 + quad * 8];

  float m_i[2][4], l_i[2][4];
  floatx4 o[2][4];
#pragma unroll
  for (int i = 0; i < 2; ++i)
#pragma unroll
    for (int r = 0; r < 4; ++r) { m_i[i][r] = -INFINITY; l_i[i][r] = 0.f; }
#pragma unroll
  for (int i = 0; i < 2; ++i)
#pragma unroll
    for (int n = 0; n < 4; ++n) o[i][n] = (floatx4)0.f;

  const ushort16* kbase = kb + ((size_t)b * kS) * kD + h * kHD;
  const ushort16* vbase = vT + (size_t)bh * kHD * kS;

  for (int k0 = 0; k0 < kS; k0 += 128) {
    // stage K tile [128 keys][64 d] as Ks[dsub][key][32]
#pragma unroll
    for (int t = 0; t < 2; ++t)
#pragma unroll
      for (int cb = 0; cb < 2; ++cb) {
        int e = cb * 2048 + tid * 8;
        async16(kbase + (size_t)(k0 + (e >> 5)) * kD + t * 32 + (e & 31),
                Ks + t * 4096 + e);
      }
    // stage V^T tile [64 d][128 s] as Vs[ssub][d][32]
#pragma unroll
    for (int t = 0; t < 4; ++t) {
      int e = tid * 8;
      async16(vbase + (size_t)(e >> 5) * kS + k0 + t * 32 + (e & 31),
              Vs + t * 2048 + e);
    }
    __syncthreads();

#pragma unroll
    for (int i = 0; i < 2; ++i) {
      // QK^T: 16 MFMA -> s[8] C-layout frags (rows i*16.., cols 128 keys)
      floatx4 s[8];
#pragma unroll
      for (int n = 0; n < 8; ++n) s[n] = (floatx4)0.f;
#pragma unroll
      for (int kkd = 0; kkd < 2; ++kkd)
#pragma unroll
        for (int n = 0; n < 8; ++n) {
          short8x bk = *(const short8x*)&Ks[kkd * 4096 + (n * 16 + c16) * 32 + quad * 8];
          s[n] = __builtin_amdgcn_mfma_f32_16x16x32_bf16(a_q[i][kkd], bk, s[n], 0, 0, 0);
        }

      // online softmax (row = quad*4 + r); write P bf16 to wave-private LDS
#pragma unroll
      for (int r = 0; r < 4; ++r) {
        float mx = s[0][r];
#pragma unroll
        for (int n = 1; n < 8; ++n) mx = fmaxf(mx, s[n][r]);
        mx = redMax16(mx);
        float mold = m_i[i][r];
        float mnew = fmaxf(mold, mx);
        float alpha = __expf(mold - mnew);
        m_i[i][r] = mnew;
        float rs = 0.f;
#pragma unroll
        for (int n = 0; n < 8; ++n) {
          float pp = __expf(s[n][r] - mnew);
          ushort16 pbv = f2b(pp);
          rs += b2f(pbv);   // l consistent with bf16-rounded P
          Ps[(wave * 4 + (n >> 1)) * 512 + (quad * 4 + r) * 32 + (n & 1) * 16 + c16] = pbv;
        }
        rs = redSum16(rs);
        l_i[i][r] = l_i[i][r] * alpha + rs;
#pragma unroll
        for (int n = 0; n < 4; ++n) o[i][n][r] *= alpha;
      }

      // PV: o[i][n] += P (A layout via LDS) @ V^T-tile (B layout)
#pragma unroll
      for (int kk = 0; kk < 4; ++kk) {
        short8x ap = *(const short8x*)&Ps[(wave * 4 + kk) * 512 + c16 * 32 + quad * 8];
#pragma unroll
        for (int n = 0; n < 4; ++n) {
          short8x bv = *(const short8x*)&Vs[kk * 2048 + (n * 16 + c16) * 32 + quad * 8];
          o[i][n] = __builtin_amdgcn_mfma_f32_16x16x32_bf16(ap, bv, o[i][n], 0, 0, 0);
        }
      }
    }
    __syncthreads();
  }

  // finalize: w = o/l; per-row roundtrip over 64 d; write f32
#pragma unroll
  for (int i = 0; i < 2; ++i)
#pragma unroll
    for (int r = 0; r < 4; ++r) {
      float invl = 1.0f / l_i[i][r];
      float w[4];
      float pssq = 0.f;
#pragma unroll
      for (int n = 0; n < 4; ++n) { w[n] = o[i][n][r] * invl; pssq += w[n] * w[n]; }
      float ssq = redSum16(pssq);
      float coef = roundtrip_scale(sqrtf(ssq)) * ratio2;
      int row = b * kS + q0 + wq + i * 16 + quad * 4 + r;
#pragma unroll
      for (int n = 0; n < 4; ++n)
        outp[(size_t)row * kD + h * kHD + n * 16 + c16] = coef * w[n];
    }
}

// ---------------- roundtrip scale, fp32 in -> bf16 out ----------------
template <int WIDTH>
__global__ __launch_bounds__(256) void k_rt_scale_f2b(const float* __restrict__ p,
                                                      ushort16* __restrict__ out) {
  __shared__ float sred[4];
  constexpr int PER = WIDTH / 256;
  size_t base = (size_t)blockIdx.x * WIDTH;
  float v[PER];
  float ss = 0.f;
#pragma unroll
  for (int i = 0; i < PER; ++i) {
    v[i] = p[base + i * 256 + threadIdx.x];
    ss += v[i] * v[i];
  }
  ss = blockReduceSum256(ss, sred);
  float s = roundtrip_scale(sqrtf(ss));
#pragma unroll
  for (int i = 0; i < PER; ++i) out[base + i * 256 + threadIdx.x] = f2b(s * v[i]);
}

// ---------------- roundtrip scale, bf16 in/out (in place) ----------------
template <int WIDTH>
__global__ __launch_bounds__(256) void k_rt_scale_b2b(ushort16* __restrict__ p) {
  __shared__ float sred[4];
  constexpr int PER = WIDTH / 256;
  size_t base = (size_t)blockIdx.x * WIDTH;
  float v[PER];
  float ss = 0.f;
#pragma unroll
  for (int i = 0; i < PER; ++i) {
    v[i] = b2f(p[base + i * 256 + threadIdx.x]);
    ss += v[i] * v[i];
  }
  ss = blockReduceSum256(ss, sred);
  float s = roundtrip_scale(sqrtf(ss));
#pragma unroll
  for (int i = 0; i < PER; ++i) p[base + i * 256 + threadIdx.x] = f2b(s * v[i]);
}

// ---------------- mobius epilogue ----------------
__global__ __launch_bounds__(256) void k_epilogue(const float* __restrict__ xres,
                                                  const float* __restrict__ ot,
                                                  const float* __restrict__ ada,
                                                  int g_off,
                                                  float* __restrict__ out) {
  __shared__ float sred[4];
  int tok = blockIdx.x;
  int b = tok >> 10;
  const float* xp = xres + (size_t)tok * kD;
  const float* op = ot + (size_t)tok * kD;
  float xv[4], tv[4];
  float ss = 0.f;
#pragma unroll
  for (int i = 0; i < 4; ++i) {
    tv[i] = op[i * 256 + threadIdx.x];
    xv[i] = xp[i * 256 + threadIdx.x];
    ss += tv[i] * tv[i];
  }
  ss = blockReduceSum256(ss, sred);
  float s5 = roundtrip_scale(sqrtf(ss));
  const float* gp = ada + b * 6 * kD + g_off;
  float at2 = 0.f;
#pragma unroll
  for (int i = 0; i < 4; ++i) {
    float a = gp[i * 256 + threadIdx.x] * s5 * tv[i];
    tv[i] = a;
    at2 += a * a;
  }
  at2 = blockReduceSum256(at2, sred);
  float nyraw = sqrtf(at2);
  float sy = expmap0_scale(nyraw);
  float ynorm = sy * nyraw;
  float y2 = ynorm * ynorm;
  float x2p = 0.f, xyp = 0.f;
#pragma unroll
  for (int i = 0; i < 4; ++i) {
    float y = sy * tv[i];
    tv[i] = y;
    x2p += xv[i] * xv[i];
    xyp += xv[i] * y;
  }
  float x2 = blockReduceSum256(x2p, sred);
  float xy = blockReduceSum256(xyp, sred);
  float cx = 1.0f + 2.0f * xy + y2;
  float cy = 1.0f - x2;
  float den = fmaxf(1.0f + 2.0f * xy + x2 * y2, EPSF);
  float invden = 1.0f / den;
  float* outp = out + (size_t)tok * kD;
#pragma unroll
  for (int i = 0; i < 4; ++i)
    outp[i * 256 + threadIdx.x] = (cx * xv[i] + cy * tv[i]) * invden;
}

// ---------------------------------------------------------------------------
extern "C" void kernel_launch(void* const* d_in, const int* in_sizes, int n_in,
                              void* d_out, int out_size, void* d_ws, size_t ws_size,
                              hipStream_t stream) {
  const float* x     = (const float*)d_in[0];
  const float* t_emb = (const float*)d_in[1];
  const float* w_q = (const float*)d_in[2];  const float* b_q = (const float*)d_in[3];
  const float* w_k = (const float*)d_in[4];  const float* b_k = (const float*)d_in[5];
  const float* w_v = (const float*)d_in[6];  const float* b_v = (const float*)d_in[7];
  const float* w_o = (const float*)d_in[8];  const float* b_o = (const float*)d_in[9];
  const float* w_f1 = (const float*)d_in[10]; const float* b_f1 = (const float*)d_in[11];
  const float* w_f2 = (const float*)d_in[12]; const float* b_f2 = (const float*)d_in[13];
  const float* w_ada = (const float*)d_in[14]; const float* b_ada = (const float*)d_in[15];
  float* out = (float*)d_out;

  constexpr size_t ND = (size_t)kN * kD;    // 4 M
  constexpr size_t NF = (size_t)kN * kFF;   // 16 M
  constexpr size_t DD = (size_t)kD * kD;    // 1 M

  float* ws   = (float*)d_ws;
  float* ada  = ws;                 // 24576 f32
  float* qt   = ada + 6 * kD * kB;  // ND f32 (qkv-GEMM q out; o-proj out; f2 out)
  float* kt   = qt + ND;            // ND f32 (k out; attn out)
  float* vt   = kt + ND;            // ND f32 (v out -> scaled in place; x_mid)
  ushort16* qbA = (ushort16*)(vt + ND);   // ND bf16 (lx / qb / rt(ao) / lx2)
  ushort16* kb  = qbA + ND;               // ND bf16
  ushort16* vTb = kb + ND;                // ND bf16 (V^T per head)
  ushort16* actB = vTb + ND;              // NF bf16 (h1)
  ushort16* wqT  = actB + NF;             // DD bf16 each
  ushort16* wkT  = wqT + DD;
  ushort16* wvT  = wkT + DD;
  ushort16* woT  = wvT + DD;
  ushort16* wf1T = woT + DD;              // FF*D
  ushort16* wf2T = wf1T + (size_t)kD * kFF;

  double bn = exp(lgamma(512.0) + lgamma(0.5) - lgamma(512.5));
  double bh = exp(lgamma(32.0) + lgamma(0.5) - lgamma(32.5));
  float R1 = (float)(bh / bn);
  float R2 = (float)(bn / bh);

  // 0) weight transpose + cast to bf16 [N][K]
  k_transpose_bf16<<<dim3(16, 16), 256, 0, stream>>>(w_q, wqT, kD, kD);
  k_transpose_bf16<<<dim3(16, 16), 256, 0, stream>>>(w_k, wkT, kD, kD);
  k_transpose_bf16<<<dim3(16, 16), 256, 0, stream>>>(w_v, wvT, kD, kD);
  k_transpose_bf16<<<dim3(16, 16), 256, 0, stream>>>(w_o, woT, kD, kD);
  k_transpose_bf16<<<dim3(64, 16), 256, 0, stream>>>(w_f1, wf1T, kD, kFF);
  k_transpose_bf16<<<dim3(16, 64), 256, 0, stream>>>(w_f2, wf2T, kFF, kD);
  // 1) ada
  k_ada<<<dim3(6 * kD / 256, kB), 256, 0, stream>>>(t_emb, w_ada, b_ada, ada);
  // 2) prenorm (msa): lx -> qbA (bf16)
  k_prenorm<<<kN, 256, 0, stream>>>(x, ada, 0 * kD, 1 * kD, qbA);
  // 3) q,k,v projections -> qt/kt/vt f32
  k_gemm_bf16<0><<<dim3(kD / 128, kN / 128, 3), 256, 0, stream>>>(
      qbA, wqT, wkT, wvT, b_q, b_k, b_v, qt, kt, vt, kN, kD, kD);
  // 4) head split: qb (bf16, pre-scaled 1/8), kb (bf16), vt scaled in place
  k_headsplit2<<<kN, 256, 0, stream>>>(qt, kt, vt, qbA, kb, R1);
  // 5) V transpose -> vTb
  k_vtrans<<<dim3(kS / 64, kB * kH), 256, 0, stream>>>(vt, vTb);
  // 6) MFMA flash attention -> kt (f32 tangent, per-head scaled)
  k_attn_mfma<<<dim3(kS / 128, kB * kH), 256, 0, stream>>>(qbA, kb, vTb, kt, R2);
  // 7) full-dim roundtrip -> qbA (bf16)
  k_rt_scale_f2b<kD><<<kN, 256, 0, stream>>>(kt, qbA);
  // 8) o projection -> qt f32
  k_gemm_bf16<0><<<dim3(kD / 128, kN / 128, 1), 256, 0, stream>>>(
      qbA, woT, woT, woT, b_o, b_o, b_o, qt, qt, qt, kN, kD, kD);
  // 9) mobius epilogue (msa): x_mid -> vt
  k_epilogue<<<kN, 256, 0, stream>>>(x, qt, ada, 2 * kD, vt);
  // 10) prenorm (mlp): lx2 -> qbA (bf16)
  k_prenorm<<<kN, 256, 0, stream>>>(vt, ada, 3 * kD, 4 * kD, qbA);
  // 11) f1 -> actB (bf16 direct)
  k_gemm_bf16<1><<<dim3(kFF / 128, kN / 128, 1), 256, 0, stream>>>(
      qbA, wf1T, wf1T, wf1T, b_f1, b_f1, b_f1, actB, actB, actB, kN, kFF, kD);
  // 12) roundtrip on h1 (bf16 in place)
  k_rt_scale_b2b<kFF><<<kN, 256, 0, stream>>>(actB);
  // 13) f2 -> qt f32
  k_gemm_bf16<0><<<dim3(kD / 128, kN / 128, 1), 256, 0, stream>>>(
      actB, wf2T, wf2T, wf2T, b_f2, b_f2, b_f2, qt, qt, qt, kN, kD, kFF);
  // 14) mobius epilogue (mlp) -> out
  k_epilogue<<<kN, 256, 0, stream>>>(vt, qt, ada, 5 * kD, out);

  (void)in_sizes; (void)n_in; (void)out_size; (void)ws_size;
}

// Round 4
// 544.562 us; speedup vs baseline: 4.0289x; 1.0670x over previous
//
#include <hip/hip_runtime.h>
#include <cmath>

// ---------------------------------------------------------------------------
// Poincare transformer layer. Round 4: split-K=2 for the two 256-block GEMMs
// (o-proj, f2) -> 2 blocks/CU co-residency; partials summed in the mobius
// epilogue (no atomics, no extra workspace).
// ---------------------------------------------------------------------------

constexpr int kD  = 1024;
constexpr int kH  = 16;
constexpr int kHD = 64;
constexpr int kFF = 4096;
constexpr int kB  = 4;
constexpr int kS  = 1024;
constexpr int kN  = kB * kS;   // 4096 tokens

#define EPSF 1e-7f
#define MTAF (1.0f - 1e-5f)

typedef unsigned int uint32;
typedef unsigned short ushort16;
typedef __attribute__((ext_vector_type(8))) short short8x;
typedef __attribute__((ext_vector_type(4))) float floatx4;

// ---------------- bf16 helpers ----------------
__device__ __forceinline__ ushort16 f2b(float f) {
  union { float f; uint32 u; } x; x.f = f;
  uint32 r = x.u + 0x7fffu + ((x.u >> 16) & 1u);   // RNE
  return (ushort16)(r >> 16);
}
__device__ __forceinline__ float b2f(ushort16 u) {
  union { uint32 u; float f; } x; x.u = ((uint32)u) << 16;
  return x.f;
}

// ---------------- math helpers ----------------
__device__ __forceinline__ float atanh_clipped(float n) {
  float c = fminf(n, MTAF);
  return 0.5f * logf((1.0f + c) / (1.0f - c));
}
__device__ __forceinline__ float logmap0_scale(float nraw) {
  float n = fmaxf(nraw, EPSF);
  return atanh_clipped(n) / n;
}
__device__ __forceinline__ float expmap0_scale(float nraw) {
  float n = fmaxf(nraw, EPSF);
  return tanhf(n) / n;
}
__device__ __forceinline__ float roundtrip_scale(float nraw) {
  float nu = fmaxf(nraw, EPSF);
  float se = tanhf(nu) / nu;
  float nb = fmaxf(se * nraw, EPSF);
  float sl = atanh_clipped(nb) / nb;
  return sl * se;
}

// ---------------- reductions ----------------
__device__ __forceinline__ float blockReduceSum256(float v, float* s4) {
#pragma unroll
  for (int o = 32; o > 0; o >>= 1) v += __shfl_xor(v, o);
  int wave = threadIdx.x >> 6;
  if ((threadIdx.x & 63) == 0) s4[wave] = v;
  __syncthreads();
  float r = s4[0] + s4[1] + s4[2] + s4[3];
  __syncthreads();
  return r;
}
__device__ __forceinline__ float waveReduceSum64(float v) {
#pragma unroll
  for (int o = 32; o > 0; o >>= 1) v += __shfl_xor(v, o);
  return v;
}
__device__ __forceinline__ float redSum16(float v) {
#pragma unroll
  for (int o = 8; o > 0; o >>= 1) v += __shfl_xor(v, o);
  return v;
}
__device__ __forceinline__ float redMax16(float v) {
#pragma unroll
  for (int o = 8; o > 0; o >>= 1) v = fmaxf(v, __shfl_xor(v, o));
  return v;
}

// ---------------- async global->LDS, 16 bytes/lane ----------------
__device__ __forceinline__ void async16(const void* g, void* l) {
  __builtin_amdgcn_global_load_lds(
      (const __attribute__((address_space(1))) uint32*)g,
      (__attribute__((address_space(3))) uint32*)l, 16, 0, 0);
}

// ---------------- weight transpose + cast: src [K][N] f32 -> dst [N][K] bf16 ----
__global__ __launch_bounds__(256) void k_transpose_bf16(const float* __restrict__ src,
                                                        ushort16* __restrict__ dst,
                                                        int K, int N) {
  __shared__ float T[64][65];
  int n0 = blockIdx.x * 64, k0 = blockIdx.y * 64;
#pragma unroll
  for (int p = 0; p < 16; ++p) {
    int idx = p * 256 + threadIdx.x;
    int r = idx >> 6, c = idx & 63;
    T[r][c] = src[(size_t)(k0 + r) * N + n0 + c];
  }
  __syncthreads();
#pragma unroll
  for (int p = 0; p < 16; ++p) {
    int idx = p * 256 + threadIdx.x;
    int r = idx >> 6, c = idx & 63;   // r: n-local, c: k-local
    dst[(size_t)(n0 + r) * K + k0 + c] = f2b(T[c][r]);
  }
}

// ---------------- ada = t_emb @ w_ada + b_ada ----------------
__global__ __launch_bounds__(256) void k_ada(const float* __restrict__ t_emb,
                                             const float* __restrict__ w_ada,
                                             const float* __restrict__ b_ada,
                                             float* __restrict__ ada) {
  __shared__ float te[kD];
  int b = blockIdx.y;
  for (int i = threadIdx.x; i < kD; i += 256) te[i] = t_emb[b * kD + i];
  __syncthreads();
  int col = blockIdx.x * 256 + threadIdx.x;
  float acc = b_ada[col];
  for (int k = 0; k < kD; ++k) acc += te[k] * w_ada[(size_t)k * (6 * kD) + col];
  ada[b * 6 * kD + col] = acc;
}

// ---------------- prenorm -> bf16 GEMM input ----------------
__global__ __launch_bounds__(256) void k_prenorm(const float* __restrict__ x,
                                                 const float* __restrict__ ada,
                                                 int sh_off, int sc_off,
                                                 ushort16* __restrict__ out) {
  __shared__ float sred[4];
  int tok = blockIdx.x;
  int b = tok >> 10;
  const float* xp = x + (size_t)tok * kD;
  float xv[4];
  float ss = 0.f;
#pragma unroll
  for (int i = 0; i < 4; ++i) {
    xv[i] = xp[i * 256 + threadIdx.x];
    ss += xv[i] * xv[i];
  }
  ss = blockReduceSum256(ss, sred);
  float sl = logmap0_scale(sqrtf(ss));
  float sum = 0.f;
#pragma unroll
  for (int i = 0; i < 4; ++i) { xv[i] *= sl; sum += xv[i]; }
  sum = blockReduceSum256(sum, sred);
  float mean = sum * (1.0f / kD);
  float vs = 0.f;
#pragma unroll
  for (int i = 0; i < 4; ++i) { xv[i] -= mean; vs += xv[i] * xv[i]; }
  vs = blockReduceSum256(vs, sred);
  float inv = rsqrtf(vs * (1.0f / kD) + 1e-6f);
  const float* shp = ada + b * 6 * kD + sh_off;
  const float* scp = ada + b * 6 * kD + sc_off;
  float uu = 0.f;
#pragma unroll
  for (int i = 0; i < 4; ++i) {
    int d = i * 256 + threadIdx.x;
    float u = xv[i] * inv * (1.0f + scp[d]) + shp[d];
    xv[i] = u;
    uu += u * u;
  }
  uu = blockReduceSum256(uu, sred);
  float s = roundtrip_scale(sqrtf(uu));
  ushort16* op = out + (size_t)tok * kD;
#pragma unroll
  for (int i = 0; i < 4; ++i) op[i * 256 + threadIdx.x] = f2b(s * xv[i]);
}

// ---------------- bf16 MFMA GEMM: C = A @ Bt^T + bias ----------------
// KSPLIT==1: blockIdx.z selects (Bt,bias,C) triple (merged qkv).
// KSPLIT==2: blockIdx.z selects K-half; z=0 -> C0 (with bias), z=1 -> C1 (no bias).
template <int OUT_BF16, int KSPLIT>
__global__ __launch_bounds__(256) void k_gemm_bf16(
    const ushort16* __restrict__ A,
    const ushort16* __restrict__ Bt0, const ushort16* __restrict__ Bt1,
    const ushort16* __restrict__ Bt2,
    const float* __restrict__ bias0, const float* __restrict__ bias1,
    const float* __restrict__ bias2,
    void* __restrict__ C0, void* __restrict__ C1, void* __restrict__ C2,
    int M, int N, int K) {
  const ushort16* Bt;
  const float* bias;
  void* C;
  int k_lo, k_hi;
  bool add_bias;
  if (KSPLIT == 1) {
    Bt = (blockIdx.z == 0) ? Bt0 : ((blockIdx.z == 1) ? Bt1 : Bt2);
    bias = (blockIdx.z == 0) ? bias0 : ((blockIdx.z == 1) ? bias1 : bias2);
    C = (blockIdx.z == 0) ? C0 : ((blockIdx.z == 1) ? C1 : C2);
    k_lo = 0; k_hi = K; add_bias = true;
  } else {
    Bt = Bt0; bias = bias0;
    C = (blockIdx.z == 0) ? C0 : C1;
    int kchunk = K / KSPLIT;
    k_lo = blockIdx.z * kchunk; k_hi = k_lo + kchunk;
    add_bias = (blockIdx.z == 0);
  }

  __shared__ __align__(16) ushort16 As[128 * 32];
  __shared__ __align__(16) ushort16 Bs[128 * 32];

  int tid = threadIdx.x;
  int lane = tid & 63;
  int wave = tid >> 6;
  int wm = (wave >> 1) * 64, wn = (wave & 1) * 64;
  int row0 = blockIdx.y * 128, col0 = blockIdx.x * 128;

  int e0 = tid * 8;
  int ar0 = e0 >> 5, ac0 = e0 & 31;
  int e1 = e0 + 2048;
  int ar1 = e1 >> 5, ac1 = e1 & 31;
  const ushort16* Ag = A + (size_t)row0 * K;
  const ushort16* Bg = Bt + (size_t)col0 * K;

  floatx4 acc[4][4];
#pragma unroll
  for (int i = 0; i < 4; ++i)
#pragma unroll
    for (int j = 0; j < 4; ++j) acc[i][j] = (floatx4)0.f;

  for (int k0 = k_lo; k0 < k_hi; k0 += 32) {
    async16(Ag + (size_t)ar0 * K + k0 + ac0, As + e0);
    async16(Ag + (size_t)ar1 * K + k0 + ac1, As + e1);
    async16(Bg + (size_t)ar0 * K + k0 + ac0, Bs + e0);
    async16(Bg + (size_t)ar1 * K + k0 + ac1, Bs + e1);
    __syncthreads();

    short8x a[4], b[4];
#pragma unroll
    for (int i = 0; i < 4; ++i) {
      a[i] = *(const short8x*)&As[(wm + i * 16 + (lane & 15)) * 32 + (lane >> 4) * 8];
      b[i] = *(const short8x*)&Bs[(wn + i * 16 + (lane & 15)) * 32 + (lane >> 4) * 8];
    }
#pragma unroll
    for (int i = 0; i < 4; ++i)
#pragma unroll
      for (int j = 0; j < 4; ++j)
        acc[i][j] = __builtin_amdgcn_mfma_f32_16x16x32_bf16(a[i], b[j], acc[i][j], 0, 0, 0);
    __syncthreads();
  }

  float bv[4];
#pragma unroll
  for (int j = 0; j < 4; ++j)
    bv[j] = add_bias ? bias[col0 + wn + j * 16 + (lane & 15)] : 0.f;
  int rowq = (lane >> 4) * 4;
#pragma unroll
  for (int i = 0; i < 4; ++i) {
    int rbase = row0 + wm + i * 16 + rowq;
#pragma unroll
    for (int j = 0; j < 4; ++j) {
      int c = col0 + wn + j * 16 + (lane & 15);
#pragma unroll
      for (int r = 0; r < 4; ++r) {
        float v = acc[i][j][r] + bv[j];
        if (OUT_BF16)
          ((ushort16*)C)[(size_t)(rbase + r) * N + c] = f2b(v);
        else
          ((float*)C)[(size_t)(rbase + r) * N + c] = v;
      }
    }
  }
}

// ---------------- head split: f32 qkv -> bf16 qb (pre-scaled 1/8), bf16 kb,
// ---------------- f32 vt in place. Folds _to_heads + logmap0 scales. ----------------
__global__ __launch_bounds__(256) void k_headsplit2(const float* __restrict__ qs,
                                                    const float* __restrict__ ks,
                                                    float* __restrict__ vs,
                                                    ushort16* __restrict__ qb,
                                                    ushort16* __restrict__ kb,
                                                    float ratio) {
  __shared__ float sh[16];
  int tok = blockIdx.x;
  int tid = threadIdx.x, wave = tid >> 6;
#pragma unroll
  for (int t = 0; t < 3; ++t) {
    const float* p = (t == 0 ? qs : (t == 1 ? ks : (const float*)vs)) + (size_t)tok * kD;
    float val[4], hs[4];
#pragma unroll
    for (int i = 0; i < 4; ++i) {
      val[i] = p[i * 256 + tid];
      hs[i] = waveReduceSum64(val[i] * val[i]);  // head (i*4 + wave) sumsq
    }
    if ((tid & 63) == 0) {
#pragma unroll
      for (int i = 0; i < 4; ++i) sh[i * 4 + wave] = hs[i];
    }
    __syncthreads();
    float tot = 0.f;
#pragma unroll
    for (int j = 0; j < 16; ++j) tot += sh[j];
    float s1 = roundtrip_scale(sqrtf(tot));
    float c = s1 * ratio;
#pragma unroll
    for (int i = 0; i < 4; ++i) {
      float m = c * sqrtf(hs[i]);
      float s2 = roundtrip_scale(m);
      float ov = c * s2 * val[i];
      size_t idx = (size_t)tok * kD + i * 256 + tid;
      if (t == 0) qb[idx] = f2b(0.125f * ov);       // fold 1/sqrt(HD)
      else if (t == 1) kb[idx] = f2b(ov);
      else vs[idx] = ov;
    }
    __syncthreads();
  }
}

// ---------------- V transpose: vt f32 [N][D] -> vT bf16 [B*H][64][S] ----------------
__global__ __launch_bounds__(256) void k_vtrans(const float* __restrict__ vt,
                                                ushort16* __restrict__ vT) {
  __shared__ float T[64][65];
  int bh = blockIdx.y, b = bh >> 4, h = bh & 15;
  int s0 = blockIdx.x * 64;
  int tid = threadIdx.x;
#pragma unroll
  for (int p = 0; p < 16; ++p) {
    int idx = p * 256 + tid;
    int r = idx >> 6, d = idx & 63;
    T[r][d] = vt[(size_t)(b * kS + s0 + r) * kD + h * kHD + d];
  }
  __syncthreads();
#pragma unroll
  for (int p = 0; p < 16; ++p) {
    int idx = p * 256 + tid;
    int d = idx >> 6, c = idx & 63;
    vT[((size_t)bh * kHD + d) * kS + s0 + c] = f2b(T[c][d]);
  }
}

// ---------------- MFMA flash attention ----------------
__global__ __launch_bounds__(256) void k_attn_mfma(const ushort16* __restrict__ qb,
                                                   const ushort16* __restrict__ kb,
                                                   const ushort16* __restrict__ vT,
                                                   float* __restrict__ outp,
                                                   float ratio2) {
  __shared__ __align__(16) ushort16 Ks[2 * 128 * 32];   // [ksub(d)][key][32]
  __shared__ __align__(16) ushort16 Vs[4 * 64 * 32];    // [ssub][d][32]
  __shared__ __align__(16) ushort16 Ps[4 * 4 * 16 * 32];// [wave][ksub(s)][row16][32]
  int bh = blockIdx.y, b = bh >> 4, h = bh & 15;
  int q0 = blockIdx.x * 128;
  int tid = threadIdx.x, lane = tid & 63, wave = tid >> 6;
  int c16 = lane & 15, quad = lane >> 4;
  int wq = wave * 32;

  short8x a_q[2][2];
#pragma unroll
  for (int i = 0; i < 2; ++i)
#pragma unroll
    for (int kk = 0; kk < 2; ++kk)
      a_q[i][kk] = *(const short8x*)&qb[(size_t)(b * kS + q0 + wq + i * 16 + c16) * kD +
                                        h * kHD + kk * 32 + quad * 8];

  float m_i[2][4], l_i[2][4];
  floatx4 o[2][4];
#pragma unroll
  for (int i = 0; i < 2; ++i)
#pragma unroll
    for (int r = 0; r < 4; ++r) { m_i[i][r] = -INFINITY; l_i[i][r] = 0.f; }
#pragma unroll
  for (int i = 0; i < 2; ++i)
#pragma unroll
    for (int n = 0; n < 4; ++n) o[i][n] = (floatx4)0.f;

  const ushort16* kbase = kb + ((size_t)b * kS) * kD + h * kHD;
  const ushort16* vbase = vT + (size_t)bh * kHD * kS;

  for (int k0 = 0; k0 < kS; k0 += 128) {
#pragma unroll
    for (int t = 0; t < 2; ++t)
#pragma unroll
      for (int cb = 0; cb < 2; ++cb) {
        int e = cb * 2048 + tid * 8;
        async16(kbase + (size_t)(k0 + (e >> 5)) * kD + t * 32 + (e & 31),
                Ks + t * 4096 + e);
      }
#pragma unroll
    for (int t = 0; t < 4; ++t) {
      int e = tid * 8;
      async16(vbase + (size_t)(e >> 5) * kS + k0 + t * 32 + (e & 31),
              Vs + t * 2048 + e);
    }
    __syncthreads();

#pragma unroll
    for (int i = 0; i < 2; ++i) {
      floatx4 s[8];
#pragma unroll
      for (int n = 0; n < 8; ++n) s[n] = (floatx4)0.f;
#pragma unroll
      for (int kkd = 0; kkd < 2; ++kkd)
#pragma unroll
        for (int n = 0; n < 8; ++n) {
          short8x bk = *(const short8x*)&Ks[kkd * 4096 + (n * 16 + c16) * 32 + quad * 8];
          s[n] = __builtin_amdgcn_mfma_f32_16x16x32_bf16(a_q[i][kkd], bk, s[n], 0, 0, 0);
        }

#pragma unroll
      for (int r = 0; r < 4; ++r) {
        float mx = s[0][r];
#pragma unroll
        for (int n = 1; n < 8; ++n) mx = fmaxf(mx, s[n][r]);
        mx = redMax16(mx);
        float mold = m_i[i][r];
        float mnew = fmaxf(mold, mx);
        float alpha = __expf(mold - mnew);
        m_i[i][r] = mnew;
        float rs = 0.f;
#pragma unroll
        for (int n = 0; n < 8; ++n) {
          float pp = __expf(s[n][r] - mnew);
          ushort16 pbv = f2b(pp);
          rs += b2f(pbv);
          Ps[(wave * 4 + (n >> 1)) * 512 + (quad * 4 + r) * 32 + (n & 1) * 16 + c16] = pbv;
        }
        rs = redSum16(rs);
        l_i[i][r] = l_i[i][r] * alpha + rs;
#pragma unroll
        for (int n = 0; n < 4; ++n) o[i][n][r] *= alpha;
      }

#pragma unroll
      for (int kk = 0; kk < 4; ++kk) {
        short8x ap = *(const short8x*)&Ps[(wave * 4 + kk) * 512 + c16 * 32 + quad * 8];
#pragma unroll
        for (int n = 0; n < 4; ++n) {
          short8x bv = *(const short8x*)&Vs[kk * 2048 + (n * 16 + c16) * 32 + quad * 8];
          o[i][n] = __builtin_amdgcn_mfma_f32_16x16x32_bf16(ap, bv, o[i][n], 0, 0, 0);
        }
      }
    }
    __syncthreads();
  }

#pragma unroll
  for (int i = 0; i < 2; ++i)
#pragma unroll
    for (int r = 0; r < 4; ++r) {
      float invl = 1.0f / l_i[i][r];
      float w[4];
      float pssq = 0.f;
#pragma unroll
      for (int n = 0; n < 4; ++n) { w[n] = o[i][n][r] * invl; pssq += w[n] * w[n]; }
      float ssq = redSum16(pssq);
      float coef = roundtrip_scale(sqrtf(ssq)) * ratio2;
      int row = b * kS + q0 + wq + i * 16 + quad * 4 + r;
#pragma unroll
      for (int n = 0; n < 4; ++n)
        outp[(size_t)row * kD + h * kHD + n * 16 + c16] = coef * w[n];
    }
}

// ---------------- roundtrip scale, fp32 in -> bf16 out ----------------
template <int WIDTH>
__global__ __launch_bounds__(256) void k_rt_scale_f2b(const float* __restrict__ p,
                                                      ushort16* __restrict__ out) {
  __shared__ float sred[4];
  constexpr int PER = WIDTH / 256;
  size_t base = (size_t)blockIdx.x * WIDTH;
  float v[PER];
  float ss = 0.f;
#pragma unroll
  for (int i = 0; i < PER; ++i) {
    v[i] = p[base + i * 256 + threadIdx.x];
    ss += v[i] * v[i];
  }
  ss = blockReduceSum256(ss, sred);
  float s = roundtrip_scale(sqrtf(ss));
#pragma unroll
  for (int i = 0; i < PER; ++i) out[base + i * 256 + threadIdx.x] = f2b(s * v[i]);
}

// ---------------- roundtrip scale, bf16 in/out (in place) ----------------
template <int WIDTH>
__global__ __launch_bounds__(256) void k_rt_scale_b2b(ushort16* __restrict__ p) {
  __shared__ float sred[4];
  constexpr int PER = WIDTH / 256;
  size_t base = (size_t)blockIdx.x * WIDTH;
  float v[PER];
  float ss = 0.f;
#pragma unroll
  for (int i = 0; i < PER; ++i) {
    v[i] = b2f(p[base + i * 256 + threadIdx.x]);
    ss += v[i] * v[i];
  }
  ss = blockReduceSum256(ss, sred);
  float s = roundtrip_scale(sqrtf(ss));
#pragma unroll
  for (int i = 0; i < PER; ++i) p[base + i * 256 + threadIdx.x] = f2b(s * v[i]);
}

// ---------------- mobius epilogue; ot = ot0 + ot1 (split-K partials) ----------------
__global__ __launch_bounds__(256) void k_epilogue2(const float* __restrict__ xres,
                                                   const float* __restrict__ ot0,
                                                   const float* __restrict__ ot1,
                                                   const float* __restrict__ ada,
                                                   int g_off,
                                                   float* __restrict__ out) {
  __shared__ float sred[4];
  int tok = blockIdx.x;
  int b = tok >> 10;
  const float* xp = xres + (size_t)tok * kD;
  const float* op0 = ot0 + (size_t)tok * kD;
  const float* op1 = ot1 + (size_t)tok * kD;
  float xv[4], tv[4];
  float ss = 0.f;
#pragma unroll
  for (int i = 0; i < 4; ++i) {
    tv[i] = op0[i * 256 + threadIdx.x] + op1[i * 256 + threadIdx.x];
    xv[i] = xp[i * 256 + threadIdx.x];
    ss += tv[i] * tv[i];
  }
  ss = blockReduceSum256(ss, sred);
  float s5 = roundtrip_scale(sqrtf(ss));
  const float* gp = ada + b * 6 * kD + g_off;
  float at2 = 0.f;
#pragma unroll
  for (int i = 0; i < 4; ++i) {
    float a = gp[i * 256 + threadIdx.x] * s5 * tv[i];
    tv[i] = a;
    at2 += a * a;
  }
  at2 = blockReduceSum256(at2, sred);
  float nyraw = sqrtf(at2);
  float sy = expmap0_scale(nyraw);
  float ynorm = sy * nyraw;
  float y2 = ynorm * ynorm;
  float x2p = 0.f, xyp = 0.f;
#pragma unroll
  for (int i = 0; i < 4; ++i) {
    float y = sy * tv[i];
    tv[i] = y;
    x2p += xv[i] * xv[i];
    xyp += xv[i] * y;
  }
  float x2 = blockReduceSum256(x2p, sred);
  float xy = blockReduceSum256(xyp, sred);
  float cx = 1.0f + 2.0f * xy + y2;
  float cy = 1.0f - x2;
  float den = fmaxf(1.0f + 2.0f * xy + x2 * y2, EPSF);
  float invden = 1.0f / den;
  float* outp = out + (size_t)tok * kD;
#pragma unroll
  for (int i = 0; i < 4; ++i)
    outp[i * 256 + threadIdx.x] = (cx * xv[i] + cy * tv[i]) * invden;
}

// ---------------------------------------------------------------------------
extern "C" void kernel_launch(void* const* d_in, const int* in_sizes, int n_in,
                              void* d_out, int out_size, void* d_ws, size_t ws_size,
                              hipStream_t stream) {
  const float* x     = (const float*)d_in[0];
  const float* t_emb = (const float*)d_in[1];
  const float* w_q = (const float*)d_in[2];  const float* b_q = (const float*)d_in[3];
  const float* w_k = (const float*)d_in[4];  const float* b_k = (const float*)d_in[5];
  const float* w_v = (const float*)d_in[6];  const float* b_v = (const float*)d_in[7];
  const float* w_o = (const float*)d_in[8];  const float* b_o = (const float*)d_in[9];
  const float* w_f1 = (const float*)d_in[10]; const float* b_f1 = (const float*)d_in[11];
  const float* w_f2 = (const float*)d_in[12]; const float* b_f2 = (const float*)d_in[13];
  const float* w_ada = (const float*)d_in[14]; const float* b_ada = (const float*)d_in[15];
  float* out = (float*)d_out;

  constexpr size_t ND = (size_t)kN * kD;    // 4 M
  constexpr size_t NF = (size_t)kN * kFF;   // 16 M
  constexpr size_t DD = (size_t)kD * kD;    // 1 M

  float* ws   = (float*)d_ws;
  float* ada  = ws;                 // 24576 f32
  float* qt   = ada + 6 * kD * kB;  // ND f32
  float* kt   = qt + ND;            // ND f32
  float* vt   = kt + ND;            // ND f32
  ushort16* qbA = (ushort16*)(vt + ND);   // ND bf16 (lx / qb / rt(ao) / lx2)
  ushort16* kb  = qbA + ND;               // ND bf16
  ushort16* vTb = kb + ND;                // ND bf16 (V^T per head)
  ushort16* actB = vTb + ND;              // NF bf16 (h1)
  ushort16* wqT  = actB + NF;             // DD bf16 each
  ushort16* wkT  = wqT + DD;
  ushort16* wvT  = wkT + DD;
  ushort16* woT  = wvT + DD;
  ushort16* wf1T = woT + DD;              // FF*D
  ushort16* wf2T = wf1T + (size_t)kD * kFF;

  double bn = exp(lgamma(512.0) + lgamma(0.5) - lgamma(512.5));
  double bh = exp(lgamma(32.0) + lgamma(0.5) - lgamma(32.5));
  float R1 = (float)(bh / bn);
  float R2 = (float)(bn / bh);

  // 0) weight transpose + cast to bf16 [N][K]
  k_transpose_bf16<<<dim3(16, 16), 256, 0, stream>>>(w_q, wqT, kD, kD);
  k_transpose_bf16<<<dim3(16, 16), 256, 0, stream>>>(w_k, wkT, kD, kD);
  k_transpose_bf16<<<dim3(16, 16), 256, 0, stream>>>(w_v, wvT, kD, kD);
  k_transpose_bf16<<<dim3(16, 16), 256, 0, stream>>>(w_o, woT, kD, kD);
  k_transpose_bf16<<<dim3(64, 16), 256, 0, stream>>>(w_f1, wf1T, kD, kFF);
  k_transpose_bf16<<<dim3(16, 64), 256, 0, stream>>>(w_f2, wf2T, kFF, kD);
  // 1) ada
  k_ada<<<dim3(6 * kD / 256, kB), 256, 0, stream>>>(t_emb, w_ada, b_ada, ada);
  // 2) prenorm (msa): lx -> qbA (bf16)
  k_prenorm<<<kN, 256, 0, stream>>>(x, ada, 0 * kD, 1 * kD, qbA);
  // 3) q,k,v projections -> qt/kt/vt f32 (z = gemm selector; 768 blocks)
  k_gemm_bf16<0, 1><<<dim3(kD / 128, kN / 128, 3), 256, 0, stream>>>(
      qbA, wqT, wkT, wvT, b_q, b_k, b_v, qt, kt, vt, kN, kD, kD);
  // 4) head split: qb (bf16, pre-scaled 1/8), kb (bf16), vt scaled in place
  k_headsplit2<<<kN, 256, 0, stream>>>(qt, kt, vt, qbA, kb, R1);
  // 5) V transpose -> vTb
  k_vtrans<<<dim3(kS / 64, kB * kH), 256, 0, stream>>>(vt, vTb);
  // 6) MFMA flash attention -> kt (f32 tangent, per-head scaled)
  k_attn_mfma<<<dim3(kS / 128, kB * kH), 256, 0, stream>>>(qbA, kb, vTb, kt, R2);
  // 7) full-dim roundtrip -> qbA (bf16)
  k_rt_scale_f2b<kD><<<kN, 256, 0, stream>>>(kt, qbA);
  // 8) o projection, split-K=2 -> partials qt (z=0, +bias) and vt (z=1); 512 blocks
  k_gemm_bf16<0, 2><<<dim3(kD / 128, kN / 128, 2), 256, 0, stream>>>(
      qbA, woT, woT, woT, b_o, b_o, b_o, qt, vt, vt, kN, kD, kD);
  // 9) mobius epilogue (msa): x_mid = mobius(x, qt+vt) -> vt (in-place safe)
  k_epilogue2<<<kN, 256, 0, stream>>>(x, qt, vt, ada, 2 * kD, vt);
  // 10) prenorm (mlp): lx2 -> qbA (bf16)
  k_prenorm<<<kN, 256, 0, stream>>>(vt, ada, 3 * kD, 4 * kD, qbA);
  // 11) f1 -> actB (bf16 direct; 1024 blocks)
  k_gemm_bf16<1, 1><<<dim3(kFF / 128, kN / 128, 1), 256, 0, stream>>>(
      qbA, wf1T, wf1T, wf1T, b_f1, b_f1, b_f1, actB, actB, actB, kN, kFF, kD);
  // 12) roundtrip on h1 (bf16 in place)
  k_rt_scale_b2b<kFF><<<kN, 256, 0, stream>>>(actB);
  // 13) f2, split-K=2 -> partials qt (z=0, +bias) and kt (z=1); 512 blocks
  k_gemm_bf16<0, 2><<<dim3(kD / 128, kN / 128, 2), 256, 0, stream>>>(
      actB, wf2T, wf2T, wf2T, b_f2, b_f2, b_f2, qt, kt, kt, kN, kD, kFF);
  // 14) mobius epilogue (mlp): out = mobius(vt, qt+kt)
  k_epilogue2<<<kN, 256, 0, stream>>>(vt, qt, kt, ada, 5 * kD, out);

  (void)in_sizes; (void)n_in; (void)out_size; (void)ws_size;
}